// Round 1
// 567.773 us; speedup vs baseline: 1.1093x; 1.1093x over previous
//
#include <hip/hip_runtime.h>
#include <hip/hip_bf16.h>

// Problem constants
#define BB 4096
#define TT 8
#define CHIN 2048
#define CC 1024
#define NN 512
#define KK 5
#define KN (KK*NN)   // 2560

typedef __bf16 bf16x8 __attribute__((ext_vector_type(8)));
typedef float  f32x4  __attribute__((ext_vector_type(4)));

// ---------------------------------------------------------------------------
// 256x256 8-wave 8-phase GEMM (C = A * B^T + bias_col), bf16 in fp32 out.
// T2 LDS XOR swizzle + T3/T4 counted-vmcnt pipeline + T5 setprio.
// ---------------------------------------------------------------------------
#define BM 256
#define BN 256
// K-tile = 64 (two 16x16x32 k-steps)

__device__ __forceinline__ void gload_lds16(const __hip_bfloat16* g, __hip_bfloat16* l) {
    __builtin_amdgcn_global_load_lds(
        (__attribute__((address_space(1))) void*)const_cast<__hip_bfloat16*>(g),
        (__attribute__((address_space(3))) void*)l, 16, 0, 0);
}

// Stage one 128x64 bf16 half-tile (row-major, row stride ldg) into LDS at l.
// global_load_lds writes LINEAR (base + lane*16); the read-side XOR swizzle is
// pre-applied to the GLOBAL source address (same involution both sides).
__device__ __forceinline__ void stage_half(const __hip_bfloat16* __restrict__ g, int ldg,
                                           __hip_bfloat16* l, int tid)
{
    #pragma unroll
    for (int q = 0; q < 2; ++q) {
        const int P   = q * 8192 + tid * 16;           // linear LDS byte offset
        const int row = P >> 7;                        // 128 B per row
        const int bc  = (P & 127) ^ ((row & 7) << 4);  // inverse swizzle on source
        gload_lds16(g + (size_t)row * ldg + (bc >> 1),
                    (__hip_bfloat16*)((char*)l + P));
    }
}

// Swizzled ds_read of one MFMA A/B fragment (8 bf16 = 16 B).
__device__ __forceinline__ bf16x8 lds_read_swz(const __hip_bfloat16* base, int row, int kbyte)
{
    int off = row * 128 + kbyte;
    off ^= (row & 7) << 4;     // lanes 0-15 (rows r..r+15) -> 2-way max (free, m136)
    return *(const bf16x8*)((const char*)base + off);
}

__device__ __forceinline__ void gemm8p_body(
    const __hip_bfloat16* __restrict__ Ag, int lda,
    const __hip_bfloat16* __restrict__ Bg, int ldb,
    float* __restrict__ Cmat, int ldc,
    int ntiles,                         // K / 64  (>= 2)
    const float* __restrict__ bias_col,
    int bm, int bn)
{
    __shared__ __align__(16) __hip_bfloat16 As[2][BM * 64];   // 64 KiB
    __shared__ __align__(16) __hip_bfloat16 Bs[2][BN * 64];   // 64 KiB

    const int tid  = threadIdx.x;
    const int wave = tid >> 6;
    const int lane = tid & 63;
    const int wrow = (wave >> 2) * 128;   // 2 waves in M
    const int wcol = (wave & 3) * 64;     // 4 waves in N
    const int fr   = lane & 15;
    const int kb0  = (lane >> 4) * 16;    // quad k-byte offset

    const __hip_bfloat16* Arow = Ag + (size_t)bm * lda;
    const __hip_bfloat16* Brow = Bg + (size_t)bn * ldb;

    f32x4 acc[8][4];
    #pragma unroll
    for (int i = 0; i < 8; ++i)
        #pragma unroll
        for (int j = 0; j < 4; ++j)
            acc[i][j] = {0.f, 0.f, 0.f, 0.f};

    bf16x8 a[4][2];     // current m-half fragments
    bf16x8 bfr[4][2];   // all 4 n-fragments (both n-halves held live)

    // Prologue: tile 0 fully, B halves of tile 1. vmcnt(4) allows the 2 newest
    // half-tiles (B of tile 1) to stay in flight.
    stage_half(Arow,                       lda, &As[0][0],        tid);
    stage_half(Arow + (size_t)128 * lda,   lda, &As[0][128 * 64], tid);
    stage_half(Brow,                       ldb, &Bs[0][0],        tid);
    stage_half(Brow + (size_t)128 * ldb,   ldb, &Bs[0][128 * 64], tid);
    if (ntiles > 1) {
        stage_half(Brow + 64,                     ldb, &Bs[1][0],        tid);
        stage_half(Brow + (size_t)128 * ldb + 64, ldb, &Bs[1][128 * 64], tid);
        asm volatile("s_waitcnt vmcnt(4)" ::: "memory");
    } else {
        asm volatile("s_waitcnt vmcnt(0)" ::: "memory");
    }
    __builtin_amdgcn_s_barrier();
    __builtin_amdgcn_sched_barrier(0);

    for (int T = 0; T < ntiles; ++T) {
        const __hip_bfloat16* Abuf = &As[T & 1][0];
        const __hip_bfloat16* Bbuf = &Bs[T & 1][0];

        // ---- phase 0: read A mh0 + B nh0, stage A-h0(T+1), MFMA Q0 (i0-3, j0-1)
        #pragma unroll
        for (int i = 0; i < 4; ++i)
            #pragma unroll
            for (int k2 = 0; k2 < 2; ++k2)
                a[i][k2] = lds_read_swz(Abuf, wrow + i * 16 + fr, k2 * 64 + kb0);
        #pragma unroll
        for (int j = 0; j < 2; ++j)
            #pragma unroll
            for (int k2 = 0; k2 < 2; ++k2)
                bfr[j][k2] = lds_read_swz(Bbuf, wcol + j * 16 + fr, k2 * 64 + kb0);
        if (T + 1 < ntiles)
            stage_half(Arow + (size_t)(T + 1) * 64, lda, &As[(T + 1) & 1][0], tid);
        __builtin_amdgcn_s_barrier();
        asm volatile("s_waitcnt lgkmcnt(0)" ::: "memory");
        __builtin_amdgcn_sched_barrier(0);
        __builtin_amdgcn_s_setprio(1);
        #pragma unroll
        for (int i = 0; i < 4; ++i)
            #pragma unroll
            for (int j = 0; j < 2; ++j)
                #pragma unroll
                for (int k2 = 0; k2 < 2; ++k2)
                    acc[i][j] = __builtin_amdgcn_mfma_f32_16x16x32_bf16(
                        a[i][k2], bfr[j][k2], acc[i][j], 0, 0, 0);
        __builtin_amdgcn_s_setprio(0);
        __builtin_amdgcn_s_barrier();
        __builtin_amdgcn_sched_barrier(0);

        // ---- phase 1: read B nh1, stage A-h1(T+1), MFMA Q1 (i0-3, j2-3)
        #pragma unroll
        for (int j = 2; j < 4; ++j)
            #pragma unroll
            for (int k2 = 0; k2 < 2; ++k2)
                bfr[j][k2] = lds_read_swz(Bbuf, wcol + j * 16 + fr, k2 * 64 + kb0);
        if (T + 1 < ntiles)
            stage_half(Arow + (size_t)128 * lda + (size_t)(T + 1) * 64, lda,
                       &As[(T + 1) & 1][128 * 64], tid);
        __builtin_amdgcn_s_barrier();
        asm volatile("s_waitcnt lgkmcnt(0)" ::: "memory");
        __builtin_amdgcn_sched_barrier(0);
        __builtin_amdgcn_s_setprio(1);
        #pragma unroll
        for (int i = 0; i < 4; ++i)
            #pragma unroll
            for (int j = 2; j < 4; ++j)
                #pragma unroll
                for (int k2 = 0; k2 < 2; ++k2)
                    acc[i][j] = __builtin_amdgcn_mfma_f32_16x16x32_bf16(
                        a[i][k2], bfr[j][k2], acc[i][j], 0, 0, 0);
        __builtin_amdgcn_s_setprio(0);
        __builtin_amdgcn_s_barrier();
        __builtin_amdgcn_sched_barrier(0);

        // ---- phase 2: read A mh1, stage B-h0(T+2) (B region of this buffer is
        //      fully consumed after phase 1's closing barrier), MFMA Q3 (i4-7, j2-3)
        #pragma unroll
        for (int i = 0; i < 4; ++i)
            #pragma unroll
            for (int k2 = 0; k2 < 2; ++k2)
                a[i][k2] = lds_read_swz(Abuf, wrow + 64 + i * 16 + fr, k2 * 64 + kb0);
        if (T + 2 < ntiles)
            stage_half(Brow + (size_t)(T + 2) * 64, ldb, &Bs[T & 1][0], tid);
        __builtin_amdgcn_s_barrier();
        asm volatile("s_waitcnt lgkmcnt(0)" ::: "memory");
        __builtin_amdgcn_sched_barrier(0);
        __builtin_amdgcn_s_setprio(1);
        #pragma unroll
        for (int i = 0; i < 4; ++i)
            #pragma unroll
            for (int j = 2; j < 4; ++j)
                #pragma unroll
                for (int k2 = 0; k2 < 2; ++k2)
                    acc[i + 4][j] = __builtin_amdgcn_mfma_f32_16x16x32_bf16(
                        a[i][k2], bfr[j][k2], acc[i + 4][j], 0, 0, 0);
        __builtin_amdgcn_s_setprio(0);
        __builtin_amdgcn_s_barrier();
        __builtin_amdgcn_sched_barrier(0);

        // ---- phase 3: stage B-h1(T+2), counted vmcnt (tile boundary), MFMA Q2
        //      (i4-7, j0-1). vmcnt(4): only the 2 newest half-tiles (B of T+2)
        //      may stay in flight -> tile T+1 fully landed.
        if (T + 2 < ntiles) {
            stage_half(Brow + (size_t)128 * ldb + (size_t)(T + 2) * 64, ldb,
                       &Bs[T & 1][128 * 64], tid);
            asm volatile("s_waitcnt vmcnt(4)" ::: "memory");
        } else if (T + 1 < ntiles) {
            asm volatile("s_waitcnt vmcnt(0)" ::: "memory");  // tail: drain A(T+1)
        }
        __builtin_amdgcn_s_barrier();
        __builtin_amdgcn_sched_barrier(0);
        __builtin_amdgcn_s_setprio(1);
        #pragma unroll
        for (int i = 0; i < 4; ++i)
            #pragma unroll
            for (int j = 0; j < 2; ++j)
                #pragma unroll
                for (int k2 = 0; k2 < 2; ++k2)
                    acc[i + 4][j] = __builtin_amdgcn_mfma_f32_16x16x32_bf16(
                        a[i][k2], bfr[j][k2], acc[i + 4][j], 0, 0, 0);
        __builtin_amdgcn_s_setprio(0);
        __builtin_amdgcn_s_barrier();
        __builtin_amdgcn_sched_barrier(0);
    }

    // Epilogue. C/D mapping: col = lane&15, row = (lane>>4)*4 + reg.
    const int quad = lane >> 4;
    #pragma unroll
    for (int i = 0; i < 8; ++i) {
        #pragma unroll
        for (int j = 0; j < 4; ++j) {
            const int col = bn + wcol + j * 16 + fr;
            const float bc = bias_col ? bias_col[col] : 0.f;
            #pragma unroll
            for (int r = 0; r < 4; ++r) {
                const int row = bm + wrow + i * 16 + quad * 4 + r;
                Cmat[(size_t)row * ldc + col] = acc[i][j][r] + bc;
            }
        }
    }
}

// Horizontally-fused launch: segment 0 = Ekv GEMM (mt0 M-tiles), segment 1 = kv GEMM.
// Both share lda=ldb=CHIN, ldc=2*CC, K=CHIN.
__global__ __launch_bounds__(512) void gemm8p_dual(
    const __hip_bfloat16* __restrict__ A0, const __hip_bfloat16* __restrict__ B0,
    float* __restrict__ C0, const float* __restrict__ bias0, int mt0,
    const __hip_bfloat16* __restrict__ A1, const __hip_bfloat16* __restrict__ B1,
    float* __restrict__ C1, const float* __restrict__ bias1)
{
    const int by = blockIdx.y;
    const bool s = by >= mt0;
    gemm8p_body(s ? A1 : A0, CHIN, s ? B1 : B0, CHIN,
                s ? C1 : C0, 2 * CC, CHIN / 64,
                s ? bias1 : bias0,
                (s ? by - mt0 : by) * BM, blockIdx.x * BN);
}

__global__ __launch_bounds__(512) void gemm8p(
    const __hip_bfloat16* __restrict__ A, int lda,
    const __hip_bfloat16* __restrict__ BT, int ldb,
    float* __restrict__ C, int ldc, int ntiles,
    const float* __restrict__ bias)
{
    gemm8p_body(A, lda, BT, ldb, C, ldc, ntiles, bias,
                blockIdx.y * BM, blockIdx.x * BN);
}

// Split-K=2: z selects K half and output buffer (summed in final_out).
__global__ __launch_bounds__(512) void gemm8p_splitk(
    const __hip_bfloat16* __restrict__ A, int lda,
    const __hip_bfloat16* __restrict__ BT, int ldb,
    float* __restrict__ C0, float* __restrict__ C1, int ldc, int khalf_tiles)
{
    const int z = blockIdx.z;
    gemm8p_body(A + (size_t)z * khalf_tiles * 64, lda,
                BT + (size_t)z * khalf_tiles * 64, ldb,
                z ? C1 : C0, ldc, khalf_tiles, nullptr,
                blockIdx.y * BM, blockIdx.x * BN);
}

// ---------------------------------------------------------------------------
// Small kernels (unchanged except final_out takes the split-K partial)
// ---------------------------------------------------------------------------

// flat fp32 -> bf16 cast, 4 elems/thread. n % 1024 == 0.
__global__ __launch_bounds__(256) void cast_f32_bf16(const float* __restrict__ in,
                                                     __hip_bfloat16* __restrict__ out, int n)
{
    const int idx = (blockIdx.x * 256 + threadIdx.x) * 4;
    if (idx >= n) return;
    const float4 vv = *(const float4*)(in + idx);
    union { __hip_bfloat16 h[4]; unsigned long long u; } pk;
    pk.h[0] = (__hip_bfloat16)vv.x; pk.h[1] = (__hip_bfloat16)vv.y;
    pk.h[2] = (__hip_bfloat16)vv.z; pk.h[3] = (__hip_bfloat16)vv.w;
    *(unsigned long long*)(out + idx) = pk.u;
}

// xb[b][i] = (bf16) x[b][T-1][i]
__global__ __launch_bounds__(256) void cast_xlast(const float* __restrict__ x,
                                                  __hip_bfloat16* __restrict__ xb)
{
    const int b = blockIdx.y;
    const int i = (blockIdx.x * 256 + threadIdx.x) * 4;
    const float4 vv = *(const float4*)(x + ((size_t)b * TT + TT - 1) * CHIN + i);
    union { __hip_bfloat16 h[4]; unsigned long long u; } pk;
    pk.h[0] = (__hip_bfloat16)vv.x; pk.h[1] = (__hip_bfloat16)vv.y;
    pk.h[2] = (__hip_bfloat16)vv.z; pk.h[3] = (__hip_bfloat16)vv.w;
    *(unsigned long long*)(xb + (size_t)b * CHIN + i) = pk.u;
}

// concat two fp32 vectors of length CC into out[0:CC]=a, out[CC:2CC]=b
__global__ __launch_bounds__(256) void concat_bias(const float* __restrict__ a,
                                                   const float* __restrict__ b,
                                                   float* __restrict__ out)
{
    const int i = blockIdx.x * 256 + threadIdx.x;  // < 2CC
    out[i] = (i < CC) ? a[i] : b[i - CC];
}

// static[k][i][n] (fp32) -> staticT[k*NN+n][i] (bf16)
__global__ void transpose_static(const float* __restrict__ st,
                                 __hip_bfloat16* __restrict__ stT)
{
    __shared__ float tile[32][33];
    const int k  = blockIdx.z;
    const int i0 = blockIdx.x * 32;
    const int n0 = blockIdx.y * 32;
    const int tx = threadIdx.x, ty = threadIdx.y;   // 32 x 8
    #pragma unroll
    for (int r = 0; r < 32; r += 8)
        tile[ty + r][tx] = st[((size_t)k * CHIN + i0 + ty + r) * NN + n0 + tx];
    __syncthreads();
    #pragma unroll
    for (int r = 0; r < 32; r += 8)
        stT[((size_t)k * NN + n0 + ty + r) * CHIN + i0 + tx] = (__hip_bfloat16)tile[tx][ty + r];
}

// bf16 [KN][CC] -> bf16 [CC][KN] transpose
__global__ void transpose_bf16(const __hip_bfloat16* __restrict__ in,
                               __hip_bfloat16* __restrict__ outp)
{
    __shared__ __hip_bfloat16 tile[32][33];
    const int c0  = blockIdx.x * 32;   // CC
    const int kn0 = blockIdx.y * 32;   // KN
    const int tx = threadIdx.x, ty = threadIdx.y;   // 32 x 8
    #pragma unroll
    for (int r = 0; r < 32; r += 8)
        tile[ty + r][tx] = in[(size_t)(kn0 + ty + r) * CC + c0 + tx];
    __syncthreads();
    #pragma unroll
    for (int r = 0; r < 32; r += 8)
        outp[(size_t)(c0 + ty + r) * KN + kn0 + tx] = tile[tx][ty + r];
}

// L2-normalize a strided row segment: in[row*in_ld + c], c in [0,cols) -> bf16 out[row*cols+c]
__global__ __launch_bounds__(256) void rownorm(const float* __restrict__ in, int in_ld,
                                               __hip_bfloat16* __restrict__ out, int cols)
{
    const int row = blockIdx.x;
    const float* p = in + (size_t)row * in_ld;
    float s = 0.f;
    for (int c = threadIdx.x; c < cols; c += 256) { float v = p[c]; s += v * v; }
    #pragma unroll
    for (int o = 32; o > 0; o >>= 1) s += __shfl_down(s, o, 64);
    __shared__ float red[4];
    if ((threadIdx.x & 63) == 0) red[threadIdx.x >> 6] = s;
    __syncthreads();
    const float tot = red[0] + red[1] + red[2] + red[3];
    const float inv = 1.f / fmaxf(sqrtf(tot), 1e-8f);
    for (int c = threadIdx.x; c < cols; c += 256)
        out[(size_t)row * cols + c] = (__hip_bfloat16)(p[c] * inv);
}

// Per kn-row: g[kn] = sum_c Ww[c]*Ekv[kn][CC+c]; EvT[kn][c] = (bf16)Ekv[kn][CC+c]
__global__ __launch_bounds__(256) void prep_gv(const float* __restrict__ Ekv,
                                               const float* __restrict__ Ww,
                                               float* __restrict__ g,
                                               __hip_bfloat16* __restrict__ EvT)
{
    const int kn = blockIdx.x;
    const float* p = Ekv + (size_t)kn * (2 * CC) + CC;
    float s = 0.f;
    for (int c = threadIdx.x; c < CC; c += 256) {
        const float v = p[c];
        s += Ww[c] * v;
        EvT[(size_t)kn * CC + c] = (__hip_bfloat16)v;
    }
    #pragma unroll
    for (int o = 32; o > 0; o >>= 1) s += __shfl_down(s, o, 64);
    __shared__ float red[4];
    if ((threadIdx.x & 63) == 0) red[threadIdx.x >> 6] = s;
    __syncthreads();
    if (threadIdx.x == 0) g[kn] = red[0] + red[1] + red[2] + red[3];
}

// per (b,k): softmax over 512, fw = sigmoid(dot(w,g)+bw), u = w*fw (bf16)
__global__ __launch_bounds__(64) void softmax_u(const float* __restrict__ sim,
                                                const float* __restrict__ g,
                                                const float* __restrict__ bw,
                                                __hip_bfloat16* __restrict__ u)
{
    const int bk = blockIdx.x;
    const int b = bk / KK, k = bk % KK;
    const float* sp = sim + (size_t)b * KN + k * NN;
    const float* gp = g + k * NN;
    const int lane = threadIdx.x;

    float vals[8];
    float m = -1e30f;
    #pragma unroll
    for (int j = 0; j < 8; ++j) { vals[j] = sp[lane + 64 * j]; m = fmaxf(m, vals[j]); }
    #pragma unroll
    for (int o = 32; o > 0; o >>= 1) m = fmaxf(m, __shfl_xor(m, o, 64));
    float sum = 0.f;
    #pragma unroll
    for (int j = 0; j < 8; ++j) { vals[j] = expf(vals[j] - m); sum += vals[j]; }
    #pragma unroll
    for (int o = 32; o > 0; o >>= 1) sum += __shfl_xor(sum, o, 64);
    const float inv = 1.f / sum;
    float dot = 0.f;
    #pragma unroll
    for (int j = 0; j < 8; ++j) { vals[j] *= inv; dot += vals[j] * gp[lane + 64 * j]; }
    #pragma unroll
    for (int o = 32; o > 0; o >>= 1) dot += __shfl_xor(dot, o, 64);
    const float fw = 1.f / (1.f + expf(-(dot + bw[0])));
    __hip_bfloat16* up = u + (size_t)b * KN + k * NN;
    #pragma unroll
    for (int j = 0; j < 8; ++j) up[lane + 64 * j] = (__hip_bfloat16)(vals[j] * fw);
}

// out[b][kk] = bout[kk] + sum_c Wout[kk][c]*relu(kv[b][CC+c]) + Wout[kk][CC+c]*relu(fE0+fE1)
__global__ __launch_bounds__(256) void final_out(const float* __restrict__ kv,
                                                 const float* __restrict__ fE0,
                                                 const float* __restrict__ fE1,
                                                 const float* __restrict__ Wout,
                                                 const float* __restrict__ bout,
                                                 float* __restrict__ out)
{
    const int b = blockIdx.x;
    const float* vp = kv + (size_t)b * (2 * CC) + CC;
    float acc[KK] = {0.f, 0.f, 0.f, 0.f, 0.f};
    for (int c = threadIdx.x; c < CC; c += 256) {
        const float rv = fmaxf(vp[c], 0.f);
        const float rf = fmaxf(fE0[(size_t)b * CC + c] + fE1[(size_t)b * CC + c], 0.f);
        #pragma unroll
        for (int kk = 0; kk < KK; ++kk)
            acc[kk] += Wout[kk * 2 * CC + c] * rv
                     + Wout[kk * 2 * CC + CC + c] * rf;
    }
    __shared__ float red[KK][4];
    const int lane = threadIdx.x & 63, wave = threadIdx.x >> 6;
    #pragma unroll
    for (int kk = 0; kk < KK; ++kk) {
        float s = acc[kk];
        #pragma unroll
        for (int o = 32; o > 0; o >>= 1) s += __shfl_down(s, o, 64);
        if (lane == 0) red[kk][wave] = s;
    }
    __syncthreads();
    if (threadIdx.x < KK) {
        float s = red[threadIdx.x][0] + red[threadIdx.x][1]
                + red[threadIdx.x][2] + red[threadIdx.x][3];
        out[(size_t)b * KK + threadIdx.x] = s + bout[threadIdx.x];
    }
}

extern "C" void kernel_launch(void* const* d_in, const int* in_sizes, int n_in,
                              void* d_out, int out_size, void* d_ws, size_t ws_size,
                              hipStream_t stream)
{
    const float* x    = (const float*)d_in[0];
    const float* stat = (const float*)d_in[1];
    const float* Wk   = (const float*)d_in[2];
    const float* bk   = (const float*)d_in[3];
    const float* Wv   = (const float*)d_in[4];
    const float* bv   = (const float*)d_in[5];
    const float* WEk  = (const float*)d_in[6];
    const float* bEk  = (const float*)d_in[7];
    const float* WEv  = (const float*)d_in[8];
    const float* bEv  = (const float*)d_in[9];
    const float* Ww   = (const float*)d_in[10];
    const float* bw   = (const float*)d_in[11];
    const float* Wout = (const float*)d_in[12];
    const float* bout = (const float*)d_in[13];
    float* out = (float*)d_out;
    char* ws = (char*)d_ws;

    // Linear workspace layout (~220 MB; ws is ~1 GB per the harness poison size).
    __hip_bfloat16* xb      = (__hip_bfloat16*)(ws + 0);          // [BB][CHIN]    16.78 MB
    __hip_bfloat16* Wkvb    = (__hip_bfloat16*)(ws + 16777216);   // [2CC][CHIN]    8.39 MB
    __hip_bfloat16* WEkvb   = (__hip_bfloat16*)(ws + 25165824);   // [2CC][CHIN]    8.39 MB
    __hip_bfloat16* staticT = (__hip_bfloat16*)(ws + 33554432);   // [KN][CHIN]    10.49 MB
    float*          Ekv     = (float*)(ws + 44040192);            // [KN][2CC]     20.97 MB
    __hip_bfloat16* EknT    = (__hip_bfloat16*)(ws + 65011712);   // [KN][CC]       5.24 MB
    __hip_bfloat16* EvT     = (__hip_bfloat16*)(ws + 70254592);   // [KN][CC]       5.24 MB
    __hip_bfloat16* EvC     = (__hip_bfloat16*)(ws + 75497472);   // [CC][KN]       5.24 MB
    float*          g       = (float*)(ws + 80740352);            // [KN]           10 KB
    float*          kv      = (float*)(ws + 80750592);            // [BB][2CC]     33.55 MB
    __hip_bfloat16* kn      = (__hip_bfloat16*)(ws + 114305024);  // [BB][CC]       8.39 MB
    float*          sim     = (float*)(ws + 122693632);           // [BB][KN]      41.94 MB
    __hip_bfloat16* u       = (__hip_bfloat16*)(ws + 164636672);  // [BB][KN]      20.97 MB
    float*          fE      = (float*)(ws + 185608192);           // [BB][CC]      16.78 MB
    float*          bkv     = (float*)(ws + 202385408);           // [2CC]          8 KB
    float*          bEkv    = (float*)(ws + 202393600);           // [2CC]          8 KB
    float*          fE2     = (float*)(ws + 202401792);           // [BB][CC]      16.78 MB

    const int WN = CC * CHIN;  // elems per weight matrix

    // 0. input prep: casts + bias concats + static transpose
    cast_f32_bf16<<<WN / 1024, 256, 0, stream>>>(Wk,  Wkvb,       WN);
    cast_f32_bf16<<<WN / 1024, 256, 0, stream>>>(Wv,  Wkvb + WN,  WN);
    cast_f32_bf16<<<WN / 1024, 256, 0, stream>>>(WEk, WEkvb,      WN);
    cast_f32_bf16<<<WN / 1024, 256, 0, stream>>>(WEv, WEkvb + WN, WN);
    cast_xlast<<<dim3(CHIN / 1024, BB), 256, 0, stream>>>(x, xb);
    concat_bias<<<2 * CC / 256, 256, 0, stream>>>(bk, bv, bkv);
    concat_bias<<<2 * CC / 256, 256, 0, stream>>>(bEk, bEv, bEkv);
    transpose_static<<<dim3(CHIN / 32, NN / 32, KK), dim3(32, 8), 0, stream>>>(stat, staticT);

    // 1+5. Fused: Ekv (M=KN, 10 M-tiles) + kv (M=BB, 16 M-tiles); N=2CC, K=CHIN.
    gemm8p_dual<<<dim3(2 * CC / BN, KN / BM + BB / BM), 512, 0, stream>>>(
        staticT, WEkvb, Ekv, bEkv, KN / BM,
        xb, Wkvb, kv, bkv);
    // 2. EknT[kn][c] = Ek row-normalized (bf16)
    rownorm<<<KN, 256, 0, stream>>>(Ekv, 2 * CC, EknT, CC);
    // 3. g[kn] = Ww . Ev[kn,:]; EvT bf16
    prep_gv<<<KN, 256, 0, stream>>>(Ekv, Ww, g, EvT);
    // 4. EvC[c][kn] = EvT[kn][c]
    transpose_bf16<<<dim3(CC / 32, KN / 32), dim3(32, 8), 0, stream>>>(EvT, EvC);
    // 6. kn = rownormalize(k_pre) (bf16)
    rownorm<<<BB, 256, 0, stream>>>(kv, 2 * CC, kn, CC);
    // 7. sim = kn @ EknT^T  (M=BB, N=KN, K=CC)
    gemm8p<<<dim3(KN / BN, BB / BM), 512, 0, stream>>>(
        kn, CC, EknT, CC, sim, KN, CC / 64, nullptr);
    // 8. softmax + fw -> u (bf16)
    softmax_u<<<BB * KK, 64, 0, stream>>>(sim, g, bw, u);
    // 9. fE + fE2 = u @ EvC^T  (M=BB, N=CC, K=KN, split-K=2)
    gemm8p_splitk<<<dim3(CC / BN, BB / BM, 2), 512, 0, stream>>>(
        u, KN, EvC, KN, fE, fE2, CC, (KN / 2) / 64);
    // 10. out = relu([v, fE+fE2]) @ Wout^T + bout (fp32 out)
    final_out<<<BB, 256, 0, stream>>>(kv, fE, fE2, Wout, bout, out);
}

// Round 2
// 548.877 us; speedup vs baseline: 1.1475x; 1.0344x over previous
//
#include <hip/hip_runtime.h>
#include <hip/hip_bf16.h>

// Problem constants
#define BB 4096
#define TT 8
#define CHIN 2048
#define CC 1024
#define NN 512
#define KK 5
#define KN (KK*NN)   // 2560

typedef __bf16 bf16x8 __attribute__((ext_vector_type(8)));
typedef float  f32x4  __attribute__((ext_vector_type(4)));

// ---------------------------------------------------------------------------
// 256x256 8-wave 8-phase GEMM (C = A * B^T + bias_col), bf16 in fp32 out.
// T2 LDS XOR swizzle + T3/T4 counted-vmcnt pipeline + T5 setprio + T1 XCD swizzle.
// ---------------------------------------------------------------------------
#define BM 256
#define BN 256
// K-tile = 64 (two 16x16x32 k-steps)

__device__ __forceinline__ void gload_lds16(const __hip_bfloat16* g, __hip_bfloat16* l) {
    __builtin_amdgcn_global_load_lds(
        (__attribute__((address_space(1))) void*)const_cast<__hip_bfloat16*>(g),
        (__attribute__((address_space(3))) void*)l, 16, 0, 0);
}

// Stage one 128x64 bf16 half-tile (row-major, row stride ldg) into LDS at l.
// global_load_lds writes LINEAR (base + lane*16); the read-side XOR swizzle is
// pre-applied to the GLOBAL source address (same involution both sides).
__device__ __forceinline__ void stage_half(const __hip_bfloat16* __restrict__ g, int ldg,
                                           __hip_bfloat16* l, int tid)
{
    #pragma unroll
    for (int q = 0; q < 2; ++q) {
        const int P   = q * 8192 + tid * 16;           // linear LDS byte offset
        const int row = P >> 7;                        // 128 B per row
        const int bc  = (P & 127) ^ ((row & 7) << 4);  // inverse swizzle on source
        gload_lds16(g + (size_t)row * ldg + (bc >> 1),
                    (__hip_bfloat16*)((char*)l + P));
    }
}

// Swizzled ds_read of one MFMA A/B fragment (8 bf16 = 16 B).
__device__ __forceinline__ bf16x8 lds_read_swz(const __hip_bfloat16* base, int row, int kbyte)
{
    int off = row * 128 + kbyte;
    off ^= (row & 7) << 4;     // lanes 0-15 (rows r..r+15) -> 2-way max (free, m136)
    return *(const bf16x8*)((const char*)base + off);
}

// T1 chunked XCD swizzle (bijective; requires nwg % 8 == 0, true for all grids here).
// Returns the remapped linear work id.
__device__ __forceinline__ int xcd_remap()
{
    const int gx = gridDim.x, gy = gridDim.y, gz = gridDim.z;
    const int lin = blockIdx.x + gx * (blockIdx.y + gy * blockIdx.z);
    const int nwg = gx * gy * gz;
    return (lin & 7) * (nwg >> 3) + (lin >> 3);
}

__device__ __forceinline__ void gemm8p_body(
    const __hip_bfloat16* __restrict__ Ag, int lda,
    const __hip_bfloat16* __restrict__ Bg, int ldb,
    float* __restrict__ Cmat, int ldc,
    int ntiles,                         // K / 64  (>= 2)
    const float* __restrict__ bias_col,
    int bm, int bn)
{
    __shared__ __align__(16) __hip_bfloat16 As[2][BM * 64];   // 64 KiB
    __shared__ __align__(16) __hip_bfloat16 Bs[2][BN * 64];   // 64 KiB

    const int tid  = threadIdx.x;
    const int wave = tid >> 6;
    const int lane = tid & 63;
    const int wrow = (wave >> 2) * 128;   // 2 waves in M
    const int wcol = (wave & 3) * 64;     // 4 waves in N
    const int fr   = lane & 15;
    const int kb0  = (lane >> 4) * 16;    // quad k-byte offset

    const __hip_bfloat16* Arow = Ag + (size_t)bm * lda;
    const __hip_bfloat16* Brow = Bg + (size_t)bn * ldb;

    f32x4 acc[8][4];
    #pragma unroll
    for (int i = 0; i < 8; ++i)
        #pragma unroll
        for (int j = 0; j < 4; ++j)
            acc[i][j] = {0.f, 0.f, 0.f, 0.f};

    bf16x8 a[4][2];     // current m-half fragments
    bf16x8 bfr[4][2];   // all 4 n-fragments (both n-halves held live)

    // Prologue: tile 0 fully, B halves of tile 1. vmcnt(4) allows the 2 newest
    // half-tiles (B of tile 1) to stay in flight.
    stage_half(Arow,                       lda, &As[0][0],        tid);
    stage_half(Arow + (size_t)128 * lda,   lda, &As[0][128 * 64], tid);
    stage_half(Brow,                       ldb, &Bs[0][0],        tid);
    stage_half(Brow + (size_t)128 * ldb,   ldb, &Bs[0][128 * 64], tid);
    if (ntiles > 1) {
        stage_half(Brow + 64,                     ldb, &Bs[1][0],        tid);
        stage_half(Brow + (size_t)128 * ldb + 64, ldb, &Bs[1][128 * 64], tid);
        asm volatile("s_waitcnt vmcnt(4)" ::: "memory");
    } else {
        asm volatile("s_waitcnt vmcnt(0)" ::: "memory");
    }
    __builtin_amdgcn_s_barrier();
    __builtin_amdgcn_sched_barrier(0);

    for (int T = 0; T < ntiles; ++T) {
        const __hip_bfloat16* Abuf = &As[T & 1][0];
        const __hip_bfloat16* Bbuf = &Bs[T & 1][0];

        // ---- phase 0: read A mh0 + B nh0, stage A-h0(T+1), MFMA Q0 (i0-3, j0-1)
        #pragma unroll
        for (int i = 0; i < 4; ++i)
            #pragma unroll
            for (int k2 = 0; k2 < 2; ++k2)
                a[i][k2] = lds_read_swz(Abuf, wrow + i * 16 + fr, k2 * 64 + kb0);
        #pragma unroll
        for (int j = 0; j < 2; ++j)
            #pragma unroll
            for (int k2 = 0; k2 < 2; ++k2)
                bfr[j][k2] = lds_read_swz(Bbuf, wcol + j * 16 + fr, k2 * 64 + kb0);
        if (T + 1 < ntiles)
            stage_half(Arow + (size_t)(T + 1) * 64, lda, &As[(T + 1) & 1][0], tid);
        __builtin_amdgcn_s_barrier();
        asm volatile("s_waitcnt lgkmcnt(0)" ::: "memory");
        __builtin_amdgcn_sched_barrier(0);
        __builtin_amdgcn_s_setprio(1);
        #pragma unroll
        for (int i = 0; i < 4; ++i)
            #pragma unroll
            for (int j = 0; j < 2; ++j)
                #pragma unroll
                for (int k2 = 0; k2 < 2; ++k2)
                    acc[i][j] = __builtin_amdgcn_mfma_f32_16x16x32_bf16(
                        a[i][k2], bfr[j][k2], acc[i][j], 0, 0, 0);
        __builtin_amdgcn_s_setprio(0);
        __builtin_amdgcn_s_barrier();
        __builtin_amdgcn_sched_barrier(0);

        // ---- phase 1: read B nh1, stage A-h1(T+1), MFMA Q1 (i0-3, j2-3)
        #pragma unroll
        for (int j = 2; j < 4; ++j)
            #pragma unroll
            for (int k2 = 0; k2 < 2; ++k2)
                bfr[j][k2] = lds_read_swz(Bbuf, wcol + j * 16 + fr, k2 * 64 + kb0);
        if (T + 1 < ntiles)
            stage_half(Arow + (size_t)128 * lda + (size_t)(T + 1) * 64, lda,
                       &As[(T + 1) & 1][128 * 64], tid);
        __builtin_amdgcn_s_barrier();
        asm volatile("s_waitcnt lgkmcnt(0)" ::: "memory");
        __builtin_amdgcn_sched_barrier(0);
        __builtin_amdgcn_s_setprio(1);
        #pragma unroll
        for (int i = 0; i < 4; ++i)
            #pragma unroll
            for (int j = 2; j < 4; ++j)
                #pragma unroll
                for (int k2 = 0; k2 < 2; ++k2)
                    acc[i][j] = __builtin_amdgcn_mfma_f32_16x16x32_bf16(
                        a[i][k2], bfr[j][k2], acc[i][j], 0, 0, 0);
        __builtin_amdgcn_s_setprio(0);
        __builtin_amdgcn_s_barrier();
        __builtin_amdgcn_sched_barrier(0);

        // ---- phase 2: read A mh1, stage B-h0(T+2) (B region of this buffer is
        //      fully consumed after phase 1's closing barrier), MFMA Q3 (i4-7, j2-3)
        #pragma unroll
        for (int i = 0; i < 4; ++i)
            #pragma unroll
            for (int k2 = 0; k2 < 2; ++k2)
                a[i][k2] = lds_read_swz(Abuf, wrow + 64 + i * 16 + fr, k2 * 64 + kb0);
        if (T + 2 < ntiles)
            stage_half(Brow + (size_t)(T + 2) * 64, ldb, &Bs[T & 1][0], tid);
        __builtin_amdgcn_s_barrier();
        asm volatile("s_waitcnt lgkmcnt(0)" ::: "memory");
        __builtin_amdgcn_sched_barrier(0);
        __builtin_amdgcn_s_setprio(1);
        #pragma unroll
        for (int i = 0; i < 4; ++i)
            #pragma unroll
            for (int j = 2; j < 4; ++j)
                #pragma unroll
                for (int k2 = 0; k2 < 2; ++k2)
                    acc[i + 4][j] = __builtin_amdgcn_mfma_f32_16x16x32_bf16(
                        a[i][k2], bfr[j][k2], acc[i + 4][j], 0, 0, 0);
        __builtin_amdgcn_s_setprio(0);
        __builtin_amdgcn_s_barrier();
        __builtin_amdgcn_sched_barrier(0);

        // ---- phase 3: stage B-h1(T+2), counted vmcnt (tile boundary), MFMA Q2
        //      (i4-7, j0-1). vmcnt(4): only the 2 newest half-tiles (B of T+2)
        //      may stay in flight -> tile T+1 fully landed.
        if (T + 2 < ntiles) {
            stage_half(Brow + (size_t)128 * ldb + (size_t)(T + 2) * 64, ldb,
                       &Bs[T & 1][128 * 64], tid);
            asm volatile("s_waitcnt vmcnt(4)" ::: "memory");
        } else if (T + 1 < ntiles) {
            asm volatile("s_waitcnt vmcnt(0)" ::: "memory");  // tail: drain A(T+1)
        }
        __builtin_amdgcn_s_barrier();
        __builtin_amdgcn_sched_barrier(0);
        __builtin_amdgcn_s_setprio(1);
        #pragma unroll
        for (int i = 0; i < 4; ++i)
            #pragma unroll
            for (int j = 0; j < 2; ++j)
                #pragma unroll
                for (int k2 = 0; k2 < 2; ++k2)
                    acc[i + 4][j] = __builtin_amdgcn_mfma_f32_16x16x32_bf16(
                        a[i][k2], bfr[j][k2], acc[i + 4][j], 0, 0, 0);
        __builtin_amdgcn_s_setprio(0);
        __builtin_amdgcn_s_barrier();
        __builtin_amdgcn_sched_barrier(0);
    }

    // Epilogue. C/D mapping: col = lane&15, row = (lane>>4)*4 + reg.
    const int quad = lane >> 4;
    #pragma unroll
    for (int i = 0; i < 8; ++i) {
        #pragma unroll
        for (int j = 0; j < 4; ++j) {
            const int col = bn + wcol + j * 16 + fr;
            const float bc = bias_col ? bias_col[col] : 0.f;
            #pragma unroll
            for (int r = 0; r < 4; ++r) {
                const int row = bm + wrow + i * 16 + quad * 4 + r;
                Cmat[(size_t)row * ldc + col] = acc[i][j][r] + bc;
            }
        }
    }
}

// Horizontally-fused launch: segment 0 = Ekv GEMM (mt0 M-tiles), segment 1 = kv GEMM.
// Both share lda=ldb=CHIN, ldc=2*CC, K=CHIN. grid (8, 26); T1-swizzled so each XCD
// owns a contiguous by-chunk (A-panel reuse in its L2) instead of one bx column.
__global__ __launch_bounds__(512) void gemm8p_dual(
    const __hip_bfloat16* __restrict__ A0, const __hip_bfloat16* __restrict__ B0,
    float* __restrict__ C0, const float* __restrict__ bias0, int mt0,
    const __hip_bfloat16* __restrict__ A1, const __hip_bfloat16* __restrict__ B1,
    float* __restrict__ C1, const float* __restrict__ bias1)
{
    const int W  = xcd_remap();
    const int bx = W % gridDim.x;
    const int by = W / gridDim.x;
    const bool s = by >= mt0;
    gemm8p_body(s ? A1 : A0, CHIN, s ? B1 : B0, CHIN,
                s ? C1 : C0, 2 * CC, CHIN / 64,
                s ? bias1 : bias0,
                (s ? by - mt0 : by) * BM, bx * BN);
}

__global__ __launch_bounds__(512) void gemm8p(
    const __hip_bfloat16* __restrict__ A, int lda,
    const __hip_bfloat16* __restrict__ BT, int ldb,
    float* __restrict__ C, int ldc, int ntiles,
    const float* __restrict__ bias)
{
    const int W  = xcd_remap();
    const int bx = W % gridDim.x;
    const int by = W / gridDim.x;
    gemm8p_body(A, lda, BT, ldb, C, ldc, ntiles, bias, by * BM, bx * BN);
}

// Split-K=2: z selects K half and output buffer (summed in final_out).
__global__ __launch_bounds__(512) void gemm8p_splitk(
    const __hip_bfloat16* __restrict__ A, int lda,
    const __hip_bfloat16* __restrict__ BT, int ldb,
    float* __restrict__ C0, float* __restrict__ C1, int ldc, int khalf_tiles)
{
    const int W   = xcd_remap();
    const int gxy = gridDim.x * gridDim.y;
    const int z   = W / gxy;
    const int rem = W % gxy;
    const int bx  = rem % gridDim.x;
    const int by  = rem / gridDim.x;
    gemm8p_body(A + (size_t)z * khalf_tiles * 64, lda,
                BT + (size_t)z * khalf_tiles * 64, ldb,
                z ? C1 : C0, ldc, khalf_tiles, nullptr,
                by * BM, bx * BN);
}

// ---------------------------------------------------------------------------
// Fused flat prep: 4 weight casts + x-last cast + 2 bias concats, one launch.
// Work unit = one float4 group. Layout:
//   [0, 4*WG)              : Wk,Wv,WEk,WEv -> Wkvb/WEkvb (bf16)
//   [4*WG, 4*WG+XG)        : x[:, T-1, :]  -> xb (bf16)
//   [4*WG+XG, +1024)       : bk|bv -> bkv ; bEk|bEv -> bEkv (fp32)
// ---------------------------------------------------------------------------
#define WG ((CC*CHIN)/4)       // 524288
#define XG ((BB*CHIN)/4)       // 2097152
#define PREP_BLOCKS ((4*WG + XG + 1024) / 256)   // 16388

__device__ __forceinline__ void store_bf4(__hip_bfloat16* dst, float4 vv) {
    union { __hip_bfloat16 h[4]; unsigned long long u; } pk;
    pk.h[0] = (__hip_bfloat16)vv.x; pk.h[1] = (__hip_bfloat16)vv.y;
    pk.h[2] = (__hip_bfloat16)vv.z; pk.h[3] = (__hip_bfloat16)vv.w;
    *(unsigned long long*)dst = pk.u;
}

__global__ __launch_bounds__(256) void prep_flat(
    const float* __restrict__ Wk, const float* __restrict__ Wv,
    const float* __restrict__ WEk, const float* __restrict__ WEv,
    const float* __restrict__ x,
    const float* __restrict__ bk, const float* __restrict__ bv,
    const float* __restrict__ bEk, const float* __restrict__ bEv,
    __hip_bfloat16* __restrict__ Wkvb, __hip_bfloat16* __restrict__ WEkvb,
    __hip_bfloat16* __restrict__ xb,
    float* __restrict__ bkv, float* __restrict__ bEkv)
{
    const int gidx = blockIdx.x * 256 + threadIdx.x;
    if (gidx < 4 * WG) {
        const int mat = gidx >> 19;               // / WG (pow2)
        const int off = (gidx & (WG - 1)) * 4;
        const float* src = (mat == 0) ? Wk : (mat == 1) ? Wv : (mat == 2) ? WEk : WEv;
        __hip_bfloat16* dst = (mat < 2) ? (Wkvb + (size_t)mat * (CC * CHIN))
                                        : (WEkvb + (size_t)(mat - 2) * (CC * CHIN));
        store_bf4(dst + off, *(const float4*)(src + off));
    } else if (gidx < 4 * WG + XG) {
        const int off = (gidx - 4 * WG) * 4;
        const int b = off >> 11;                  // / CHIN
        const int i = off & (CHIN - 1);
        store_bf4(xb + off, *(const float4*)(x + ((size_t)b * TT + TT - 1) * CHIN + i));
    } else {
        const int off = (gidx - 4 * WG - XG) * 4;
        #pragma unroll
        for (int e = 0; e < 4; ++e) {
            const int t = off + e;
            if (t < 2 * CC) bkv[t]  = (t < CC) ? bk[t] : bv[t - CC];
            else { const int u2 = t - 2 * CC; bEkv[u2] = (u2 < CC) ? bEk[u2] : bEv[u2 - CC]; }
        }
    }
}

// static[k][i][n] (fp32) -> staticT[k*NN+n][i] (bf16)
__global__ void transpose_static(const float* __restrict__ st,
                                 __hip_bfloat16* __restrict__ stT)
{
    __shared__ float tile[32][33];
    const int k  = blockIdx.z;
    const int i0 = blockIdx.x * 32;
    const int n0 = blockIdx.y * 32;
    const int tx = threadIdx.x, ty = threadIdx.y;   // 32 x 8
    #pragma unroll
    for (int r = 0; r < 32; r += 8)
        tile[ty + r][tx] = st[((size_t)k * CHIN + i0 + ty + r) * NN + n0 + tx];
    __syncthreads();
    #pragma unroll
    for (int r = 0; r < 32; r += 8)
        stT[((size_t)k * NN + n0 + ty + r) * CHIN + i0 + tx] = (__hip_bfloat16)tile[tx][ty + r];
}

// bf16 [KN][CC] -> bf16 [CC][KN] transpose
__global__ void transpose_bf16(const __hip_bfloat16* __restrict__ in,
                               __hip_bfloat16* __restrict__ outp)
{
    __shared__ __hip_bfloat16 tile[32][33];
    const int c0  = blockIdx.x * 32;   // CC
    const int kn0 = blockIdx.y * 32;   // KN
    const int tx = threadIdx.x, ty = threadIdx.y;   // 32 x 8
    #pragma unroll
    for (int r = 0; r < 32; r += 8)
        tile[ty + r][tx] = in[(size_t)(kn0 + ty + r) * CC + c0 + tx];
    __syncthreads();
    #pragma unroll
    for (int r = 0; r < 32; r += 8)
        outp[(size_t)(c0 + ty + r) * KN + kn0 + tx] = tile[tx][ty + r];
}

// Merged per-kn-row pass over Ekv: EknT = normalized Ek (bf16); g = Ww.Ev; EvT = bf16(Ev)
__global__ __launch_bounds__(256) void norm_prep_E(const float* __restrict__ Ekv,
                                                   const float* __restrict__ Ww,
                                                   __hip_bfloat16* __restrict__ EknT,
                                                   float* __restrict__ g,
                                                   __hip_bfloat16* __restrict__ EvT)
{
    const int kn = blockIdx.x;
    const float* pk = Ekv + (size_t)kn * (2 * CC);
    const float* pv = pk + CC;
    float s2 = 0.f, sg = 0.f;
    for (int c = threadIdx.x; c < CC; c += 256) {
        const float ek = pk[c]; s2 += ek * ek;
        const float ev = pv[c]; sg += Ww[c] * ev;
        EvT[(size_t)kn * CC + c] = (__hip_bfloat16)ev;
    }
    #pragma unroll
    for (int o = 32; o > 0; o >>= 1) { s2 += __shfl_down(s2, o, 64); sg += __shfl_down(sg, o, 64); }
    __shared__ float r2[4], rg[4];
    if ((threadIdx.x & 63) == 0) { r2[threadIdx.x >> 6] = s2; rg[threadIdx.x >> 6] = sg; }
    __syncthreads();
    const float tot = r2[0] + r2[1] + r2[2] + r2[3];
    const float inv = 1.f / fmaxf(sqrtf(tot), 1e-8f);
    for (int c = threadIdx.x; c < CC; c += 256)
        EknT[(size_t)kn * CC + c] = (__hip_bfloat16)(pk[c] * inv);
    if (threadIdx.x == 0) g[kn] = rg[0] + rg[1] + rg[2] + rg[3];
}

// L2-normalize a strided row segment: in[row*in_ld + c], c in [0,cols) -> bf16 out[row*cols+c]
__global__ __launch_bounds__(256) void rownorm(const float* __restrict__ in, int in_ld,
                                               __hip_bfloat16* __restrict__ out, int cols)
{
    const int row = blockIdx.x;
    const float* p = in + (size_t)row * in_ld;
    float s = 0.f;
    for (int c = threadIdx.x; c < cols; c += 256) { float v = p[c]; s += v * v; }
    #pragma unroll
    for (int o = 32; o > 0; o >>= 1) s += __shfl_down(s, o, 64);
    __shared__ float red[4];
    if ((threadIdx.x & 63) == 0) red[threadIdx.x >> 6] = s;
    __syncthreads();
    const float tot = red[0] + red[1] + red[2] + red[3];
    const float inv = 1.f / fmaxf(sqrtf(tot), 1e-8f);
    for (int c = threadIdx.x; c < cols; c += 256)
        out[(size_t)row * cols + c] = (__hip_bfloat16)(p[c] * inv);
}

// per (b,k): softmax over 512, fw = sigmoid(dot(w,g)+bw), u = w*fw (bf16)
__global__ __launch_bounds__(64) void softmax_u(const float* __restrict__ sim,
                                                const float* __restrict__ g,
                                                const float* __restrict__ bw,
                                                __hip_bfloat16* __restrict__ u)
{
    const int bk = blockIdx.x;
    const int b = bk / KK, k = bk % KK;
    const float* sp = sim + (size_t)b * KN + k * NN;
    const float* gp = g + k * NN;
    const int lane = threadIdx.x;

    float vals[8];
    float m = -1e30f;
    #pragma unroll
    for (int j = 0; j < 8; ++j) { vals[j] = sp[lane + 64 * j]; m = fmaxf(m, vals[j]); }
    #pragma unroll
    for (int o = 32; o > 0; o >>= 1) m = fmaxf(m, __shfl_xor(m, o, 64));
    float sum = 0.f;
    #pragma unroll
    for (int j = 0; j < 8; ++j) { vals[j] = expf(vals[j] - m); sum += vals[j]; }
    #pragma unroll
    for (int o = 32; o > 0; o >>= 1) sum += __shfl_xor(sum, o, 64);
    const float inv = 1.f / sum;
    float dot = 0.f;
    #pragma unroll
    for (int j = 0; j < 8; ++j) { vals[j] *= inv; dot += vals[j] * gp[lane + 64 * j]; }
    #pragma unroll
    for (int o = 32; o > 0; o >>= 1) dot += __shfl_xor(dot, o, 64);
    const float fw = 1.f / (1.f + expf(-(dot + bw[0])));
    __hip_bfloat16* up = u + (size_t)b * KN + k * NN;
    #pragma unroll
    for (int j = 0; j < 8; ++j) up[lane + 64 * j] = (__hip_bfloat16)(vals[j] * fw);
}

// out[b][kk] = bout[kk] + sum_c Wout[kk][c]*relu(kv[b][CC+c]) + Wout[kk][CC+c]*relu(fE0+fE1)
__global__ __launch_bounds__(256) void final_out(const float* __restrict__ kv,
                                                 const float* __restrict__ fE0,
                                                 const float* __restrict__ fE1,
                                                 const float* __restrict__ Wout,
                                                 const float* __restrict__ bout,
                                                 float* __restrict__ out)
{
    const int b = blockIdx.x;
    const float* vp = kv + (size_t)b * (2 * CC) + CC;
    float acc[KK] = {0.f, 0.f, 0.f, 0.f, 0.f};
    for (int c = threadIdx.x; c < CC; c += 256) {
        const float rv = fmaxf(vp[c], 0.f);
        const float rf = fmaxf(fE0[(size_t)b * CC + c] + fE1[(size_t)b * CC + c], 0.f);
        #pragma unroll
        for (int kk = 0; kk < KK; ++kk)
            acc[kk] += Wout[kk * 2 * CC + c] * rv
                     + Wout[kk * 2 * CC + CC + c] * rf;
    }
    __shared__ float red[KK][4];
    const int lane = threadIdx.x & 63, wave = threadIdx.x >> 6;
    #pragma unroll
    for (int kk = 0; kk < KK; ++kk) {
        float s = acc[kk];
        #pragma unroll
        for (int o = 32; o > 0; o >>= 1) s += __shfl_down(s, o, 64);
        if (lane == 0) red[kk][wave] = s;
    }
    __syncthreads();
    if (threadIdx.x < KK) {
        float s = red[threadIdx.x][0] + red[threadIdx.x][1]
                + red[threadIdx.x][2] + red[threadIdx.x][3];
        out[(size_t)b * KK + threadIdx.x] = s + bout[threadIdx.x];
    }
}

extern "C" void kernel_launch(void* const* d_in, const int* in_sizes, int n_in,
                              void* d_out, int out_size, void* d_ws, size_t ws_size,
                              hipStream_t stream)
{
    const float* x    = (const float*)d_in[0];
    const float* stat = (const float*)d_in[1];
    const float* Wk   = (const float*)d_in[2];
    const float* bk   = (const float*)d_in[3];
    const float* Wv   = (const float*)d_in[4];
    const float* bv   = (const float*)d_in[5];
    const float* WEk  = (const float*)d_in[6];
    const float* bEk  = (const float*)d_in[7];
    const float* WEv  = (const float*)d_in[8];
    const float* bEv  = (const float*)d_in[9];
    const float* Ww   = (const float*)d_in[10];
    const float* bw   = (const float*)d_in[11];
    const float* Wout = (const float*)d_in[12];
    const float* bout = (const float*)d_in[13];
    float* out = (float*)d_out;
    char* ws = (char*)d_ws;

    // Linear workspace layout (~220 MB; ws is ~1 GB per the harness poison size).
    __hip_bfloat16* xb      = (__hip_bfloat16*)(ws + 0);          // [BB][CHIN]    16.78 MB
    __hip_bfloat16* Wkvb    = (__hip_bfloat16*)(ws + 16777216);   // [2CC][CHIN]    8.39 MB
    __hip_bfloat16* WEkvb   = (__hip_bfloat16*)(ws + 25165824);   // [2CC][CHIN]    8.39 MB
    __hip_bfloat16* staticT = (__hip_bfloat16*)(ws + 33554432);   // [KN][CHIN]    10.49 MB
    float*          Ekv     = (float*)(ws + 44040192);            // [KN][2CC]     20.97 MB
    __hip_bfloat16* EknT    = (__hip_bfloat16*)(ws + 65011712);   // [KN][CC]       5.24 MB
    __hip_bfloat16* EvT     = (__hip_bfloat16*)(ws + 70254592);   // [KN][CC]       5.24 MB
    __hip_bfloat16* EvC     = (__hip_bfloat16*)(ws + 75497472);   // [CC][KN]       5.24 MB
    float*          g       = (float*)(ws + 80740352);            // [KN]           10 KB
    float*          kv      = (float*)(ws + 80750592);            // [BB][2CC]     33.55 MB
    __hip_bfloat16* kn      = (__hip_bfloat16*)(ws + 114305024);  // [BB][CC]       8.39 MB
    float*          sim     = (float*)(ws + 122693632);           // [BB][KN]      41.94 MB
    __hip_bfloat16* u       = (__hip_bfloat16*)(ws + 164636672);  // [BB][KN]      20.97 MB
    float*          fE      = (float*)(ws + 185608192);           // [BB][CC]      16.78 MB
    float*          bkv     = (float*)(ws + 202385408);           // [2CC]          8 KB
    float*          bEkv    = (float*)(ws + 202393600);           // [2CC]          8 KB
    float*          fE2     = (float*)(ws + 202401792);           // [BB][CC]      16.78 MB

    // 0. all flat prep in one launch + static transpose
    prep_flat<<<PREP_BLOCKS, 256, 0, stream>>>(
        Wk, Wv, WEk, WEv, x, bk, bv, bEk, bEv, Wkvb, WEkvb, xb, bkv, bEkv);
    transpose_static<<<dim3(CHIN / 32, NN / 32, KK), dim3(32, 8), 0, stream>>>(stat, staticT);

    // 1+5. Fused: Ekv (M=KN, 10 M-tiles) + kv (M=BB, 16 M-tiles); N=2CC, K=CHIN.
    gemm8p_dual<<<dim3(2 * CC / BN, KN / BM + BB / BM), 512, 0, stream>>>(
        staticT, WEkvb, Ekv, bEkv, KN / BM,
        xb, Wkvb, kv, bkv);
    // 2+3. Ek row-norm + g + EvT in one pass
    norm_prep_E<<<KN, 256, 0, stream>>>(Ekv, Ww, EknT, g, EvT);
    // 4. EvC[c][kn] = EvT[kn][c]
    transpose_bf16<<<dim3(CC / 32, KN / 32), dim3(32, 8), 0, stream>>>(EvT, EvC);
    // 6. kn = rownormalize(k_pre) (bf16)
    rownorm<<<BB, 256, 0, stream>>>(kv, 2 * CC, kn, CC);
    // 7. sim = kn @ EknT^T  (M=BB, N=KN, K=CC)
    gemm8p<<<dim3(KN / BN, BB / BM), 512, 0, stream>>>(
        kn, CC, EknT, CC, sim, KN, CC / 64, nullptr);
    // 8. softmax + fw -> u (bf16)
    softmax_u<<<BB * KK, 64, 0, stream>>>(sim, g, bw, u);
    // 9. fE + fE2 = u @ EvC^T  (M=BB, N=CC, K=KN, split-K=2)
    gemm8p_splitk<<<dim3(CC / BN, BB / BM, 2), 512, 0, stream>>>(
        u, KN, EvC, KN, fE, fE2, CC, (KN / 2) / 64);
    // 10. out = relu([v, fE+fE2]) @ Wout^T + bout (fp32 out)
    final_out<<<BB, 256, 0, stream>>>(kv, fE, fE2, Wout, bout, out);
}

// Round 3
// 540.130 us; speedup vs baseline: 1.1661x; 1.0162x over previous
//
#include <hip/hip_runtime.h>
#include <hip/hip_bf16.h>

// Problem constants
#define BB 4096
#define TT 8
#define CHIN 2048
#define CC 1024
#define NN 512
#define KK 5
#define KN (KK*NN)   // 2560

typedef __bf16 bf16x8 __attribute__((ext_vector_type(8)));
typedef float  f32x4  __attribute__((ext_vector_type(4)));

// ---------------------------------------------------------------------------
// 256x256 8-wave GEMM (C = A * B^T + bias_col), bf16 in fp32 out.
// T2 LDS XOR swizzle + T3/T4 counted-vmcnt (2-tile-deep prefetch) + T5 setprio
// + T1 XCD chunk swizzle.
// ---------------------------------------------------------------------------
#define BM 256
#define BN 256
// K-tile = 64 (two 16x16x32 k-steps); staging granularity = 64x64 quarter.

__device__ __forceinline__ void gload_lds16(const __hip_bfloat16* g, __hip_bfloat16* l) {
    __builtin_amdgcn_global_load_lds(
        (__attribute__((address_space(1))) void*)const_cast<__hip_bfloat16*>(g),
        (__attribute__((address_space(3))) void*)l, 16, 0, 0);
}

// Stage one 64x64 bf16 quarter (row-major, row stride ldg) into LDS at l.
// 512 threads x 16B = 8 KiB. LDS dest is LINEAR; the read-side XOR swizzle is
// pre-applied to the GLOBAL source address (same involution both sides).
__device__ __forceinline__ void stage_q(const __hip_bfloat16* __restrict__ g, int ldg,
                                        __hip_bfloat16* l, int tid)
{
    const int P   = tid * 16;                      // linear LDS byte offset
    const int row = P >> 7;                        // 128 B per row
    const int bc  = (P & 127) ^ ((row & 7) << 4);  // inverse swizzle on source
    gload_lds16(g + (size_t)row * ldg + (bc >> 1),
                (__hip_bfloat16*)((char*)l + P));
}

// T1 chunked XCD swizzle (bijective; requires nwg % 8 == 0, true for all grids).
__device__ __forceinline__ int xcd_remap()
{
    const int gx = gridDim.x, gy = gridDim.y, gz = gridDim.z;
    const int lin = blockIdx.x + gx * (blockIdx.y + gy * blockIdx.z);
    const int nwg = gx * gy * gz;
    return (lin & 7) * (nwg >> 3) + (lin >> 3);
}

__device__ __forceinline__ void gemm8p_body(
    const __hip_bfloat16* __restrict__ Ag, int lda,
    const __hip_bfloat16* __restrict__ Bg, int ldb,
    float* __restrict__ Cmat, int ldc,
    int ntiles,                         // K / 64  (>= 2 here)
    const float* __restrict__ bias_col,
    int bm, int bn)
{
    __shared__ __align__(16) __hip_bfloat16 As[2][BM * 64];   // 64 KiB
    __shared__ __align__(16) __hip_bfloat16 Bs[2][BN * 64];   // 64 KiB

    const int tid  = threadIdx.x;
    const int wave = tid >> 6;
    const int lane = tid & 63;
    const int wrow = (wave >> 2) * 128;   // 2 waves in M
    const int wcol = (wave & 3) * 64;     // 4 waves in N
    const int fr   = lane & 15;
    const int kb0  = (lane >> 4) * 16;    // quad k-byte offset

    const __hip_bfloat16* Arow = Ag + (size_t)bm * lda;
    const __hip_bfloat16* Brow = Bg + (size_t)bn * ldb;

    // Hoisted swizzled LDS byte offsets (tile-invariant; row+16i / row+64 keep
    // row&7, so i/half deltas are pure adds foldable into ds_read immediates).
    const int rA = wrow + fr, rB = wcol + fr;
    const int swA = (rA & 7) << 4, swB = (rB & 7) << 4;
    const int offA0 = rA * 128 + ((kb0     ) ^ swA);
    const int offA1 = rA * 128 + ((kb0 + 64) ^ swA);
    const int offB0 = rB * 128 + ((kb0     ) ^ swB);
    const int offB1 = rB * 128 + ((kb0 + 64) ^ swB);

    f32x4 acc[8][4];
    #pragma unroll
    for (int i = 0; i < 8; ++i)
        #pragma unroll
        for (int j = 0; j < 4; ++j)
            acc[i][j] = {0.f, 0.f, 0.f, 0.f};

    bf16x8 a[4][2];     // current m-half fragments
    bf16x8 b01[2][2];   // n-frags j=0,1 (read P0, used P0+P3)
    bf16x8 b23[2][2];   // n-frags j=2,3 (read P1, used P1+P2)

    // ---- Prologue: fully stage tiles 0 and 1 (8 quarter-loads each).
    // vmcnt(8) retires tile 0, leaves tile 1's 8 loads in flight.
    #pragma unroll
    for (int q = 0; q < 4; ++q)
        stage_q(Arow + (size_t)(64 * q) * lda, lda, &As[0][q * 4096], tid);
    #pragma unroll
    for (int q = 0; q < 4; ++q)
        stage_q(Brow + (size_t)(64 * q) * ldb, ldb, &Bs[0][q * 4096], tid);
    if (ntiles > 1) {
        #pragma unroll
        for (int q = 0; q < 4; ++q)
            stage_q(Arow + (size_t)(64 * q) * lda + 64, lda, &As[1][q * 4096], tid);
        #pragma unroll
        for (int q = 0; q < 4; ++q)
            stage_q(Brow + (size_t)(64 * q) * ldb + 64, ldb, &Bs[1][q * 4096], tid);
        asm volatile("s_waitcnt vmcnt(8)" ::: "memory");
    } else {
        asm volatile("s_waitcnt vmcnt(0)" ::: "memory");
    }
    __builtin_amdgcn_s_barrier();
    __builtin_amdgcn_sched_barrier(0);

    // Steady state: all stages target tile T+2 (same parity as T), 8 loads/tile
    // in flight -> one vmcnt(8) per tile (at P3) guarantees tile T+1 landed.
    // Region liveness: A-mh0 quarters (q0,q2) free after P0-close; all B free
    // after P1-close; A-mh1 quarters (q1,q3) free after P2-close.
    for (int T = 0; T < ntiles; ++T) {
        const char* aB = (const char*)&As[T & 1][0];
        const char* bB = (const char*)&Bs[T & 1][0];
        const char* aK0 = aB + offA0; const char* aK1 = aB + offA1;
        const char* bK0 = bB + offB0; const char* bK1 = bB + offB1;
        const bool pf = (T + 2 < ntiles);
        const int  kc = (T + 2) * 64;

        // ---- P0: read a-mh0 (8) + b01 (4); no stage; MFMA Q(i0-3, j0-1)
        #pragma unroll
        for (int i = 0; i < 4; ++i) {
            a[i][0] = *(const bf16x8*)(aK0 + i * 2048);
            a[i][1] = *(const bf16x8*)(aK1 + i * 2048);
        }
        #pragma unroll
        for (int j = 0; j < 2; ++j) {
            b01[j][0] = *(const bf16x8*)(bK0 + j * 2048);
            b01[j][1] = *(const bf16x8*)(bK1 + j * 2048);
        }
        __builtin_amdgcn_s_barrier();
        asm volatile("s_waitcnt lgkmcnt(0)" ::: "memory");
        __builtin_amdgcn_sched_barrier(0);
        __builtin_amdgcn_s_setprio(1);
        #pragma unroll
        for (int i = 0; i < 4; ++i)
            #pragma unroll
            for (int j = 0; j < 2; ++j)
                #pragma unroll
                for (int k2 = 0; k2 < 2; ++k2)
                    acc[i][j] = __builtin_amdgcn_mfma_f32_16x16x32_bf16(
                        a[i][k2], b01[j][k2], acc[i][j], 0, 0, 0);
        __builtin_amdgcn_s_setprio(0);
        __builtin_amdgcn_s_barrier();
        __builtin_amdgcn_sched_barrier(0);

        // ---- P1: read b23 (4); stage A q0,q2 (T+2); MFMA Q(i0-3, j2-3)
        #pragma unroll
        for (int j = 0; j < 2; ++j) {
            b23[j][0] = *(const bf16x8*)(bK0 + (j + 2) * 2048);
            b23[j][1] = *(const bf16x8*)(bK1 + (j + 2) * 2048);
        }
        if (pf) {
            stage_q(Arow + kc,                       lda, &As[T & 1][0],        tid);
            stage_q(Arow + (size_t)128 * lda + kc,   lda, &As[T & 1][2 * 4096], tid);
        }
        __builtin_amdgcn_s_barrier();
        asm volatile("s_waitcnt lgkmcnt(0)" ::: "memory");
        __builtin_amdgcn_sched_barrier(0);
        __builtin_amdgcn_s_setprio(1);
        #pragma unroll
        for (int i = 0; i < 4; ++i)
            #pragma unroll
            for (int j = 0; j < 2; ++j)
                #pragma unroll
                for (int k2 = 0; k2 < 2; ++k2)
                    acc[i][j + 2] = __builtin_amdgcn_mfma_f32_16x16x32_bf16(
                        a[i][k2], b23[j][k2], acc[i][j + 2], 0, 0, 0);
        __builtin_amdgcn_s_setprio(0);
        __builtin_amdgcn_s_barrier();
        __builtin_amdgcn_sched_barrier(0);

        // ---- P2: read a-mh1 (8); stage B q0..q3 (T+2); MFMA Q(i4-7, j2-3)
        #pragma unroll
        for (int i = 0; i < 4; ++i) {
            a[i][0] = *(const bf16x8*)(aK0 + 8192 + i * 2048);
            a[i][1] = *(const bf16x8*)(aK1 + 8192 + i * 2048);
        }
        if (pf) {
            #pragma unroll
            for (int q = 0; q < 4; ++q)
                stage_q(Brow + (size_t)(64 * q) * ldb + kc, ldb, &Bs[T & 1][q * 4096], tid);
        }
        __builtin_amdgcn_s_barrier();
        asm volatile("s_waitcnt lgkmcnt(0)" ::: "memory");
        __builtin_amdgcn_sched_barrier(0);
        __builtin_amdgcn_s_setprio(1);
        #pragma unroll
        for (int i = 0; i < 4; ++i)
            #pragma unroll
            for (int j = 0; j < 2; ++j)
                #pragma unroll
                for (int k2 = 0; k2 < 2; ++k2)
                    acc[i + 4][j + 2] = __builtin_amdgcn_mfma_f32_16x16x32_bf16(
                        a[i][k2], b23[j][k2], acc[i + 4][j + 2], 0, 0, 0);
        __builtin_amdgcn_s_setprio(0);
        __builtin_amdgcn_s_barrier();
        __builtin_amdgcn_sched_barrier(0);

        // ---- P3: stage A q1,q3 (T+2); counted vmcnt (8 = this tile's loads);
        //      MFMA Q(i4-7, j0-1) from registers (no new ds_reads).
        if (pf) {
            stage_q(Arow + (size_t)64 * lda + kc,    lda, &As[T & 1][4096],     tid);
            stage_q(Arow + (size_t)192 * lda + kc,   lda, &As[T & 1][3 * 4096], tid);
            asm volatile("s_waitcnt vmcnt(8)" ::: "memory");
        } else if (T + 1 < ntiles) {
            asm volatile("s_waitcnt vmcnt(0)" ::: "memory");  // tail drain
        }
        __builtin_amdgcn_s_barrier();
        __builtin_amdgcn_sched_barrier(0);
        __builtin_amdgcn_s_setprio(1);
        #pragma unroll
        for (int i = 0; i < 4; ++i)
            #pragma unroll
            for (int j = 0; j < 2; ++j)
                #pragma unroll
                for (int k2 = 0; k2 < 2; ++k2)
                    acc[i + 4][j] = __builtin_amdgcn_mfma_f32_16x16x32_bf16(
                        a[i][k2], b01[j][k2], acc[i + 4][j], 0, 0, 0);
        __builtin_amdgcn_s_setprio(0);
        __builtin_amdgcn_s_barrier();
        __builtin_amdgcn_sched_barrier(0);
    }

    // Epilogue. C/D mapping: col = lane&15, row = (lane>>4)*4 + reg.
    const int quad = lane >> 4;
    #pragma unroll
    for (int i = 0; i < 8; ++i) {
        #pragma unroll
        for (int j = 0; j < 4; ++j) {
            const int col = bn + wcol + j * 16 + fr;
            const float bc = bias_col ? bias_col[col] : 0.f;
            #pragma unroll
            for (int r = 0; r < 4; ++r) {
                const int row = bm + wrow + i * 16 + quad * 4 + r;
                Cmat[(size_t)row * ldc + col] = acc[i][j][r] + bc;
            }
        }
    }
}

// Horizontally-fused launch: segment 0 = Ekv GEMM (mt0 M-tiles), segment 1 = kv GEMM.
__global__ __launch_bounds__(512) void gemm8p_dual(
    const __hip_bfloat16* __restrict__ A0, const __hip_bfloat16* __restrict__ B0,
    float* __restrict__ C0, const float* __restrict__ bias0, int mt0,
    const __hip_bfloat16* __restrict__ A1, const __hip_bfloat16* __restrict__ B1,
    float* __restrict__ C1, const float* __restrict__ bias1)
{
    const int W  = xcd_remap();
    const int bx = W % gridDim.x;
    const int by = W / gridDim.x;
    const bool s = by >= mt0;
    gemm8p_body(s ? A1 : A0, CHIN, s ? B1 : B0, CHIN,
                s ? C1 : C0, 2 * CC, CHIN / 64,
                s ? bias1 : bias0,
                (s ? by - mt0 : by) * BM, bx * BN);
}

__global__ __launch_bounds__(512) void gemm8p(
    const __hip_bfloat16* __restrict__ A, int lda,
    const __hip_bfloat16* __restrict__ BT, int ldb,
    float* __restrict__ C, int ldc, int ntiles,
    const float* __restrict__ bias)
{
    const int W  = xcd_remap();
    const int bx = W % gridDim.x;
    const int by = W / gridDim.x;
    gemm8p_body(A, lda, BT, ldb, C, ldc, ntiles, bias, by * BM, bx * BN);
}

// Split-K=2: z selects K half and output buffer (summed in final_out).
__global__ __launch_bounds__(512) void gemm8p_splitk(
    const __hip_bfloat16* __restrict__ A, int lda,
    const __hip_bfloat16* __restrict__ BT, int ldb,
    float* __restrict__ C0, float* __restrict__ C1, int ldc, int khalf_tiles)
{
    const int W   = xcd_remap();
    const int gxy = gridDim.x * gridDim.y;
    const int z   = W / gxy;
    const int rem = W % gxy;
    const int bx  = rem % gridDim.x;
    const int by  = rem / gridDim.x;
    gemm8p_body(A + (size_t)z * khalf_tiles * 64, lda,
                BT + (size_t)z * khalf_tiles * 64, ldb,
                z ? C1 : C0, ldc, khalf_tiles, nullptr,
                by * BM, bx * BN);
}

// ---------------------------------------------------------------------------
// Fused flat prep: 4 weight casts + x-last cast + 2 bias concats, one launch.
// ---------------------------------------------------------------------------
#define WG ((CC*CHIN)/4)       // 524288
#define XG ((BB*CHIN)/4)       // 2097152
#define PREP_BLOCKS ((4*WG + XG + 1024) / 256)   // 16388

__device__ __forceinline__ void store_bf4(__hip_bfloat16* dst, float4 vv) {
    union { __hip_bfloat16 h[4]; unsigned long long u; } pk;
    pk.h[0] = (__hip_bfloat16)vv.x; pk.h[1] = (__hip_bfloat16)vv.y;
    pk.h[2] = (__hip_bfloat16)vv.z; pk.h[3] = (__hip_bfloat16)vv.w;
    *(unsigned long long*)dst = pk.u;
}

__global__ __launch_bounds__(256) void prep_flat(
    const float* __restrict__ Wk, const float* __restrict__ Wv,
    const float* __restrict__ WEk, const float* __restrict__ WEv,
    const float* __restrict__ x,
    const float* __restrict__ bk, const float* __restrict__ bv,
    const float* __restrict__ bEk, const float* __restrict__ bEv,
    __hip_bfloat16* __restrict__ Wkvb, __hip_bfloat16* __restrict__ WEkvb,
    __hip_bfloat16* __restrict__ xb,
    float* __restrict__ bkv, float* __restrict__ bEkv)
{
    const int gidx = blockIdx.x * 256 + threadIdx.x;
    if (gidx < 4 * WG) {
        const int mat = gidx >> 19;               // / WG (pow2)
        const int off = (gidx & (WG - 1)) * 4;
        const float* src = (mat == 0) ? Wk : (mat == 1) ? Wv : (mat == 2) ? WEk : WEv;
        __hip_bfloat16* dst = (mat < 2) ? (Wkvb + (size_t)mat * (CC * CHIN))
                                        : (WEkvb + (size_t)(mat - 2) * (CC * CHIN));
        store_bf4(dst + off, *(const float4*)(src + off));
    } else if (gidx < 4 * WG + XG) {
        const int off = (gidx - 4 * WG) * 4;
        const int b = off >> 11;                  // / CHIN
        const int i = off & (CHIN - 1);
        store_bf4(xb + off, *(const float4*)(x + ((size_t)b * TT + TT - 1) * CHIN + i));
    } else {
        const int off = (gidx - 4 * WG - XG) * 4;
        #pragma unroll
        for (int e = 0; e < 4; ++e) {
            const int t = off + e;
            if (t < 2 * CC) bkv[t]  = (t < CC) ? bk[t] : bv[t - CC];
            else { const int u2 = t - 2 * CC; bEkv[u2] = (u2 < CC) ? bEk[u2] : bEv[u2 - CC]; }
        }
    }
}

// static[k][i][n] (fp32) -> staticT[k*NN+n][i] (bf16)
__global__ void transpose_static(const float* __restrict__ st,
                                 __hip_bfloat16* __restrict__ stT)
{
    __shared__ float tile[32][33];
    const int k  = blockIdx.z;
    const int i0 = blockIdx.x * 32;
    const int n0 = blockIdx.y * 32;
    const int tx = threadIdx.x, ty = threadIdx.y;   // 32 x 8
    #pragma unroll
    for (int r = 0; r < 32; r += 8)
        tile[ty + r][tx] = st[((size_t)k * CHIN + i0 + ty + r) * NN + n0 + tx];
    __syncthreads();
    #pragma unroll
    for (int r = 0; r < 32; r += 8)
        stT[((size_t)k * NN + n0 + ty + r) * CHIN + i0 + tx] = (__hip_bfloat16)tile[tx][ty + r];
}

// Ev transpose straight from fp32 Ekv (cols CC..2CC): EvC[c][kn] = bf16(Ekv[kn][CC+c])
__global__ void transpose_Ev(const float* __restrict__ Ekv,
                             __hip_bfloat16* __restrict__ EvC)
{
    __shared__ float tile[32][33];
    const int c0  = blockIdx.x * 32;   // CC
    const int kn0 = blockIdx.y * 32;   // KN
    const int tx = threadIdx.x, ty = threadIdx.y;   // 32 x 8
    #pragma unroll
    for (int r = 0; r < 32; r += 8)
        tile[ty + r][tx] = Ekv[(size_t)(kn0 + ty + r) * (2 * CC) + CC + c0 + tx];
    __syncthreads();
    #pragma unroll
    for (int r = 0; r < 32; r += 8)
        EvC[(size_t)(c0 + ty + r) * KN + kn0 + tx] = (__hip_bfloat16)tile[tx][ty + r];
}

// Merged per-kn-row pass over Ekv: EknT = normalized Ek (bf16); g = Ww.Ev
__global__ __launch_bounds__(256) void norm_prep_E(const float* __restrict__ Ekv,
                                                   const float* __restrict__ Ww,
                                                   __hip_bfloat16* __restrict__ EknT,
                                                   float* __restrict__ g)
{
    const int kn = blockIdx.x;
    const float* pk = Ekv + (size_t)kn * (2 * CC);
    const float* pv = pk + CC;
    float s2 = 0.f, sg = 0.f;
    for (int c = threadIdx.x; c < CC; c += 256) {
        const float ek = pk[c]; s2 += ek * ek;
        sg += Ww[c] * pv[c];
    }
    #pragma unroll
    for (int o = 32; o > 0; o >>= 1) { s2 += __shfl_down(s2, o, 64); sg += __shfl_down(sg, o, 64); }
    __shared__ float r2[4], rg[4];
    if ((threadIdx.x & 63) == 0) { r2[threadIdx.x >> 6] = s2; rg[threadIdx.x >> 6] = sg; }
    __syncthreads();
    const float tot = r2[0] + r2[1] + r2[2] + r2[3];
    const float inv = 1.f / fmaxf(sqrtf(tot), 1e-8f);
    for (int c = threadIdx.x; c < CC; c += 256)
        EknT[(size_t)kn * CC + c] = (__hip_bfloat16)(pk[c] * inv);
    if (threadIdx.x == 0) g[kn] = rg[0] + rg[1] + rg[2] + rg[3];
}

// L2-normalize a strided row segment: in[row*in_ld + c] -> bf16 out[row*cols+c]
__global__ __launch_bounds__(256) void rownorm(const float* __restrict__ in, int in_ld,
                                               __hip_bfloat16* __restrict__ out, int cols)
{
    const int row = blockIdx.x;
    const float* p = in + (size_t)row * in_ld;
    float s = 0.f;
    for (int c = threadIdx.x; c < cols; c += 256) { float v = p[c]; s += v * v; }
    #pragma unroll
    for (int o = 32; o > 0; o >>= 1) s += __shfl_down(s, o, 64);
    __shared__ float red[4];
    if ((threadIdx.x & 63) == 0) red[threadIdx.x >> 6] = s;
    __syncthreads();
    const float tot = red[0] + red[1] + red[2] + red[3];
    const float inv = 1.f / fmaxf(sqrtf(tot), 1e-8f);
    for (int c = threadIdx.x; c < cols; c += 256)
        out[(size_t)row * cols + c] = (__hip_bfloat16)(p[c] * inv);
}

// per (b,k): softmax over 512, fw = sigmoid(dot(w,g)+bw), u = w*fw (bf16).
// 4 independent waves per block (one (b,k) each).
__global__ __launch_bounds__(256) void softmax_u(const float* __restrict__ sim,
                                                 const float* __restrict__ g,
                                                 const float* __restrict__ bw,
                                                 __hip_bfloat16* __restrict__ u)
{
    const int bk = blockIdx.x * 4 + (threadIdx.x >> 6);
    const int b = bk / KK, k = bk % KK;
    const float* sp = sim + (size_t)b * KN + k * NN;
    const float* gp = g + k * NN;
    const int lane = threadIdx.x & 63;

    float vals[8];
    float m = -1e30f;
    #pragma unroll
    for (int j = 0; j < 8; ++j) { vals[j] = sp[lane + 64 * j]; m = fmaxf(m, vals[j]); }
    #pragma unroll
    for (int o = 32; o > 0; o >>= 1) m = fmaxf(m, __shfl_xor(m, o, 64));
    float sum = 0.f;
    #pragma unroll
    for (int j = 0; j < 8; ++j) { vals[j] = expf(vals[j] - m); sum += vals[j]; }
    #pragma unroll
    for (int o = 32; o > 0; o >>= 1) sum += __shfl_xor(sum, o, 64);
    const float inv = 1.f / sum;
    float dot = 0.f;
    #pragma unroll
    for (int j = 0; j < 8; ++j) { vals[j] *= inv; dot += vals[j] * gp[lane + 64 * j]; }
    #pragma unroll
    for (int o = 32; o > 0; o >>= 1) dot += __shfl_xor(dot, o, 64);
    const float fw = 1.f / (1.f + expf(-(dot + bw[0])));
    __hip_bfloat16* up = u + (size_t)b * KN + k * NN;
    #pragma unroll
    for (int j = 0; j < 8; ++j) up[lane + 64 * j] = (__hip_bfloat16)(vals[j] * fw);
}

// out[b][kk] = bout[kk] + sum_c Wout[kk][c]*relu(kv[b][CC+c]) + Wout[kk][CC+c]*relu(fE0+fE1)
__global__ __launch_bounds__(256) void final_out(const float* __restrict__ kv,
                                                 const float* __restrict__ fE0,
                                                 const float* __restrict__ fE1,
                                                 const float* __restrict__ Wout,
                                                 const float* __restrict__ bout,
                                                 float* __restrict__ out)
{
    const int b = blockIdx.x;
    const float* vp = kv + (size_t)b * (2 * CC) + CC;
    float acc[KK] = {0.f, 0.f, 0.f, 0.f, 0.f};
    for (int c = threadIdx.x; c < CC; c += 256) {
        const float rv = fmaxf(vp[c], 0.f);
        const float rf = fmaxf(fE0[(size_t)b * CC + c] + fE1[(size_t)b * CC + c], 0.f);
        #pragma unroll
        for (int kk = 0; kk < KK; ++kk)
            acc[kk] += Wout[kk * 2 * CC + c] * rv
                     + Wout[kk * 2 * CC + CC + c] * rf;
    }
    __shared__ float red[KK][4];
    const int lane = threadIdx.x & 63, wave = threadIdx.x >> 6;
    #pragma unroll
    for (int kk = 0; kk < KK; ++kk) {
        float s = acc[kk];
        #pragma unroll
        for (int o = 32; o > 0; o >>= 1) s += __shfl_down(s, o, 64);
        if (lane == 0) red[kk][wave] = s;
    }
    __syncthreads();
    if (threadIdx.x < KK) {
        float s = red[threadIdx.x][0] + red[threadIdx.x][1]
                + red[threadIdx.x][2] + red[threadIdx.x][3];
        out[(size_t)b * KK + threadIdx.x] = s + bout[threadIdx.x];
    }
}

extern "C" void kernel_launch(void* const* d_in, const int* in_sizes, int n_in,
                              void* d_out, int out_size, void* d_ws, size_t ws_size,
                              hipStream_t stream)
{
    const float* x    = (const float*)d_in[0];
    const float* stat = (const float*)d_in[1];
    const float* Wk   = (const float*)d_in[2];
    const float* bk   = (const float*)d_in[3];
    const float* Wv   = (const float*)d_in[4];
    const float* bv   = (const float*)d_in[5];
    const float* WEk  = (const float*)d_in[6];
    const float* bEk  = (const float*)d_in[7];
    const float* WEv  = (const float*)d_in[8];
    const float* bEv  = (const float*)d_in[9];
    const float* Ww   = (const float*)d_in[10];
    const float* bw   = (const float*)d_in[11];
    const float* Wout = (const float*)d_in[12];
    const float* bout = (const float*)d_in[13];
    float* out = (float*)d_out;
    char* ws = (char*)d_ws;

    // Linear workspace layout (~220 MB; ws is ~1 GB per the harness poison size).
    __hip_bfloat16* xb      = (__hip_bfloat16*)(ws + 0);          // [BB][CHIN]    16.78 MB
    __hip_bfloat16* Wkvb    = (__hip_bfloat16*)(ws + 16777216);   // [2CC][CHIN]    8.39 MB
    __hip_bfloat16* WEkvb   = (__hip_bfloat16*)(ws + 25165824);   // [2CC][CHIN]    8.39 MB
    __hip_bfloat16* staticT = (__hip_bfloat16*)(ws + 33554432);   // [KN][CHIN]    10.49 MB
    float*          Ekv     = (float*)(ws + 44040192);            // [KN][2CC]     20.97 MB
    __hip_bfloat16* EknT    = (__hip_bfloat16*)(ws + 65011712);   // [KN][CC]       5.24 MB
    __hip_bfloat16* EvC     = (__hip_bfloat16*)(ws + 75497472);   // [CC][KN]       5.24 MB
    float*          g       = (float*)(ws + 80740352);            // [KN]           10 KB
    float*          kv      = (float*)(ws + 80750592);            // [BB][2CC]     33.55 MB
    __hip_bfloat16* kn      = (__hip_bfloat16*)(ws + 114305024);  // [BB][CC]       8.39 MB
    float*          sim     = (float*)(ws + 122693632);           // [BB][KN]      41.94 MB
    __hip_bfloat16* u       = (__hip_bfloat16*)(ws + 164636672);  // [BB][KN]      20.97 MB
    float*          fE      = (float*)(ws + 185608192);           // [BB][CC]      16.78 MB
    float*          bkv     = (float*)(ws + 202385408);           // [2CC]          8 KB
    float*          bEkv    = (float*)(ws + 202393600);           // [2CC]          8 KB
    float*          fE2     = (float*)(ws + 202401792);           // [BB][CC]      16.78 MB

    // 0. all flat prep in one launch + static transpose
    prep_flat<<<PREP_BLOCKS, 256, 0, stream>>>(
        Wk, Wv, WEk, WEv, x, bk, bv, bEk, bEv, Wkvb, WEkvb, xb, bkv, bEkv);
    transpose_static<<<dim3(CHIN / 32, NN / 32, KK), dim3(32, 8), 0, stream>>>(stat, staticT);

    // 1+5. Fused: Ekv (M=KN, 10 M-tiles) + kv (M=BB, 16 M-tiles); N=2CC, K=CHIN.
    gemm8p_dual<<<dim3(2 * CC / BN, KN / BM + BB / BM), 512, 0, stream>>>(
        staticT, WEkvb, Ekv, bEkv, KN / BM,
        xb, Wkvb, kv, bkv);
    // 2+3. Ek row-norm + g in one pass
    norm_prep_E<<<KN, 256, 0, stream>>>(Ekv, Ww, EknT, g);
    // 4. EvC[c][kn] = bf16(Ekv[kn][CC+c])
    transpose_Ev<<<dim3(CC / 32, KN / 32), dim3(32, 8), 0, stream>>>(Ekv, EvC);
    // 6. kn = rownormalize(k_pre) (bf16)
    rownorm<<<BB, 256, 0, stream>>>(kv, 2 * CC, kn, CC);
    // 7. sim = kn @ EknT^T  (M=BB, N=KN, K=CC)
    gemm8p<<<dim3(KN / BN, BB / BM), 512, 0, stream>>>(
        kn, CC, EknT, CC, sim, KN, CC / 64, nullptr);
    // 8. softmax + fw -> u (bf16)
    softmax_u<<<BB * KK / 4, 256, 0, stream>>>(sim, g, bw, u);
    // 9. fE + fE2 = u @ EvC^T  (M=BB, N=CC, K=KN, split-K=2)
    gemm8p_splitk<<<dim3(CC / BN, BB / BM, 2), 512, 0, stream>>>(
        u, KN, EvC, KN, fE, fE2, CC, (KN / 2) / 64);
    // 10. out = relu([v, fE+fE2]) @ Wout^T + bout (fp32 out)
    final_out<<<BB, 256, 0, stream>>>(kv, fE, fE2, Wout, bout, out);
}

// Round 4
// 528.455 us; speedup vs baseline: 1.1919x; 1.0221x over previous
//
#include <hip/hip_runtime.h>
#include <hip/hip_bf16.h>

// Problem constants
#define BB 4096
#define TT 8
#define CHIN 2048
#define CC 1024
#define NN 512
#define KK 5
#define KN (KK*NN)   // 2560

typedef __bf16 bf16x8 __attribute__((ext_vector_type(8)));
typedef float  f32x4  __attribute__((ext_vector_type(4)));

// ---------------------------------------------------------------------------
// 256x256 8-wave GEMM (C = A * B^T + bias_col), bf16 in fp32 out.
// T2 LDS XOR swizzle + T3/T4 counted-vmcnt (2-tile-deep prefetch) + T5 setprio
// + T1 XCD chunk swizzle.  (Unchanged from round 3 — verified correct.)
// ---------------------------------------------------------------------------
#define BM 256
#define BN 256

__device__ __forceinline__ void gload_lds16(const __hip_bfloat16* g, __hip_bfloat16* l) {
    __builtin_amdgcn_global_load_lds(
        (__attribute__((address_space(1))) void*)const_cast<__hip_bfloat16*>(g),
        (__attribute__((address_space(3))) void*)l, 16, 0, 0);
}

__device__ __forceinline__ void stage_q(const __hip_bfloat16* __restrict__ g, int ldg,
                                        __hip_bfloat16* l, int tid)
{
    const int P   = tid * 16;                      // linear LDS byte offset
    const int row = P >> 7;                        // 128 B per row
    const int bc  = (P & 127) ^ ((row & 7) << 4);  // inverse swizzle on source
    gload_lds16(g + (size_t)row * ldg + (bc >> 1),
                (__hip_bfloat16*)((char*)l + P));
}

__device__ __forceinline__ int xcd_remap()
{
    const int gx = gridDim.x, gy = gridDim.y, gz = gridDim.z;
    const int lin = blockIdx.x + gx * (blockIdx.y + gy * blockIdx.z);
    const int nwg = gx * gy * gz;
    return (lin & 7) * (nwg >> 3) + (lin >> 3);
}

__device__ __forceinline__ void gemm8p_body(
    const __hip_bfloat16* __restrict__ Ag, int lda,
    const __hip_bfloat16* __restrict__ Bg, int ldb,
    float* __restrict__ Cmat, int ldc,
    int ntiles,                         // K / 64  (>= 2 here)
    const float* __restrict__ bias_col,
    int bm, int bn)
{
    __shared__ __align__(16) __hip_bfloat16 As[2][BM * 64];   // 64 KiB
    __shared__ __align__(16) __hip_bfloat16 Bs[2][BN * 64];   // 64 KiB

    const int tid  = threadIdx.x;
    const int wave = tid >> 6;
    const int lane = tid & 63;
    const int wrow = (wave >> 2) * 128;   // 2 waves in M
    const int wcol = (wave & 3) * 64;     // 4 waves in N
    const int fr   = lane & 15;
    const int kb0  = (lane >> 4) * 16;    // quad k-byte offset

    const __hip_bfloat16* Arow = Ag + (size_t)bm * lda;
    const __hip_bfloat16* Brow = Bg + (size_t)bn * ldb;

    const int rA = wrow + fr, rB = wcol + fr;
    const int swA = (rA & 7) << 4, swB = (rB & 7) << 4;
    const int offA0 = rA * 128 + ((kb0     ) ^ swA);
    const int offA1 = rA * 128 + ((kb0 + 64) ^ swA);
    const int offB0 = rB * 128 + ((kb0     ) ^ swB);
    const int offB1 = rB * 128 + ((kb0 + 64) ^ swB);

    f32x4 acc[8][4];
    #pragma unroll
    for (int i = 0; i < 8; ++i)
        #pragma unroll
        for (int j = 0; j < 4; ++j)
            acc[i][j] = {0.f, 0.f, 0.f, 0.f};

    bf16x8 a[4][2];
    bf16x8 b01[2][2];
    bf16x8 b23[2][2];

    #pragma unroll
    for (int q = 0; q < 4; ++q)
        stage_q(Arow + (size_t)(64 * q) * lda, lda, &As[0][q * 4096], tid);
    #pragma unroll
    for (int q = 0; q < 4; ++q)
        stage_q(Brow + (size_t)(64 * q) * ldb, ldb, &Bs[0][q * 4096], tid);
    if (ntiles > 1) {
        #pragma unroll
        for (int q = 0; q < 4; ++q)
            stage_q(Arow + (size_t)(64 * q) * lda + 64, lda, &As[1][q * 4096], tid);
        #pragma unroll
        for (int q = 0; q < 4; ++q)
            stage_q(Brow + (size_t)(64 * q) * ldb + 64, ldb, &Bs[1][q * 4096], tid);
        asm volatile("s_waitcnt vmcnt(8)" ::: "memory");
    } else {
        asm volatile("s_waitcnt vmcnt(0)" ::: "memory");
    }
    __builtin_amdgcn_s_barrier();
    __builtin_amdgcn_sched_barrier(0);

    for (int T = 0; T < ntiles; ++T) {
        const char* aB = (const char*)&As[T & 1][0];
        const char* bB = (const char*)&Bs[T & 1][0];
        const char* aK0 = aB + offA0; const char* aK1 = aB + offA1;
        const char* bK0 = bB + offB0; const char* bK1 = bB + offB1;
        const bool pf = (T + 2 < ntiles);
        const int  kc = (T + 2) * 64;

        // ---- P0
        #pragma unroll
        for (int i = 0; i < 4; ++i) {
            a[i][0] = *(const bf16x8*)(aK0 + i * 2048);
            a[i][1] = *(const bf16x8*)(aK1 + i * 2048);
        }
        #pragma unroll
        for (int j = 0; j < 2; ++j) {
            b01[j][0] = *(const bf16x8*)(bK0 + j * 2048);
            b01[j][1] = *(const bf16x8*)(bK1 + j * 2048);
        }
        __builtin_amdgcn_s_barrier();
        asm volatile("s_waitcnt lgkmcnt(0)" ::: "memory");
        __builtin_amdgcn_sched_barrier(0);
        __builtin_amdgcn_s_setprio(1);
        #pragma unroll
        for (int i = 0; i < 4; ++i)
            #pragma unroll
            for (int j = 0; j < 2; ++j)
                #pragma unroll
                for (int k2 = 0; k2 < 2; ++k2)
                    acc[i][j] = __builtin_amdgcn_mfma_f32_16x16x32_bf16(
                        a[i][k2], b01[j][k2], acc[i][j], 0, 0, 0);
        __builtin_amdgcn_s_setprio(0);
        __builtin_amdgcn_s_barrier();
        __builtin_amdgcn_sched_barrier(0);

        // ---- P1
        #pragma unroll
        for (int j = 0; j < 2; ++j) {
            b23[j][0] = *(const bf16x8*)(bK0 + (j + 2) * 2048);
            b23[j][1] = *(const bf16x8*)(bK1 + (j + 2) * 2048);
        }
        if (pf) {
            stage_q(Arow + kc,                       lda, &As[T & 1][0],        tid);
            stage_q(Arow + (size_t)128 * lda + kc,   lda, &As[T & 1][2 * 4096], tid);
        }
        __builtin_amdgcn_s_barrier();
        asm volatile("s_waitcnt lgkmcnt(0)" ::: "memory");
        __builtin_amdgcn_sched_barrier(0);
        __builtin_amdgcn_s_setprio(1);
        #pragma unroll
        for (int i = 0; i < 4; ++i)
            #pragma unroll
            for (int j = 0; j < 2; ++j)
                #pragma unroll
                for (int k2 = 0; k2 < 2; ++k2)
                    acc[i][j + 2] = __builtin_amdgcn_mfma_f32_16x16x32_bf16(
                        a[i][k2], b23[j][k2], acc[i][j + 2], 0, 0, 0);
        __builtin_amdgcn_s_setprio(0);
        __builtin_amdgcn_s_barrier();
        __builtin_amdgcn_sched_barrier(0);

        // ---- P2
        #pragma unroll
        for (int i = 0; i < 4; ++i) {
            a[i][0] = *(const bf16x8*)(aK0 + 8192 + i * 2048);
            a[i][1] = *(const bf16x8*)(aK1 + 8192 + i * 2048);
        }
        if (pf) {
            #pragma unroll
            for (int q = 0; q < 4; ++q)
                stage_q(Brow + (size_t)(64 * q) * ldb + kc, ldb, &Bs[T & 1][q * 4096], tid);
        }
        __builtin_amdgcn_s_barrier();
        asm volatile("s_waitcnt lgkmcnt(0)" ::: "memory");
        __builtin_amdgcn_sched_barrier(0);
        __builtin_amdgcn_s_setprio(1);
        #pragma unroll
        for (int i = 0; i < 4; ++i)
            #pragma unroll
            for (int j = 0; j < 2; ++j)
                #pragma unroll
                for (int k2 = 0; k2 < 2; ++k2)
                    acc[i + 4][j + 2] = __builtin_amdgcn_mfma_f32_16x16x32_bf16(
                        a[i][k2], b23[j][k2], acc[i + 4][j + 2], 0, 0, 0);
        __builtin_amdgcn_s_setprio(0);
        __builtin_amdgcn_s_barrier();
        __builtin_amdgcn_sched_barrier(0);

        // ---- P3
        if (pf) {
            stage_q(Arow + (size_t)64 * lda + kc,    lda, &As[T & 1][4096],     tid);
            stage_q(Arow + (size_t)192 * lda + kc,   lda, &As[T & 1][3 * 4096], tid);
            asm volatile("s_waitcnt vmcnt(8)" ::: "memory");
        } else if (T + 1 < ntiles) {
            asm volatile("s_waitcnt vmcnt(0)" ::: "memory");
        }
        __builtin_amdgcn_s_barrier();
        __builtin_amdgcn_sched_barrier(0);
        __builtin_amdgcn_s_setprio(1);
        #pragma unroll
        for (int i = 0; i < 4; ++i)
            #pragma unroll
            for (int j = 0; j < 2; ++j)
                #pragma unroll
                for (int k2 = 0; k2 < 2; ++k2)
                    acc[i + 4][j] = __builtin_amdgcn_mfma_f32_16x16x32_bf16(
                        a[i][k2], b01[j][k2], acc[i + 4][j], 0, 0, 0);
        __builtin_amdgcn_s_setprio(0);
        __builtin_amdgcn_s_barrier();
        __builtin_amdgcn_sched_barrier(0);
    }

    const int quad = lane >> 4;
    #pragma unroll
    for (int i = 0; i < 8; ++i) {
        #pragma unroll
        for (int j = 0; j < 4; ++j) {
            const int col = bn + wcol + j * 16 + fr;
            const float bc = bias_col ? bias_col[col] : 0.f;
            #pragma unroll
            for (int r = 0; r < 4; ++r) {
                const int row = bm + wrow + i * 16 + quad * 4 + r;
                Cmat[(size_t)row * ldc + col] = acc[i][j][r] + bc;
            }
        }
    }
}

__global__ __launch_bounds__(512) void gemm8p_dual(
    const __hip_bfloat16* __restrict__ A0, const __hip_bfloat16* __restrict__ B0,
    float* __restrict__ C0, const float* __restrict__ bias0, int mt0,
    const __hip_bfloat16* __restrict__ A1, const __hip_bfloat16* __restrict__ B1,
    float* __restrict__ C1, const float* __restrict__ bias1)
{
    const int W  = xcd_remap();
    const int bx = W % gridDim.x;
    const int by = W / gridDim.x;
    const bool s = by >= mt0;
    gemm8p_body(s ? A1 : A0, CHIN, s ? B1 : B0, CHIN,
                s ? C1 : C0, 2 * CC, CHIN / 64,
                s ? bias1 : bias0,
                (s ? by - mt0 : by) * BM, bx * BN);
}

__global__ __launch_bounds__(512) void gemm8p(
    const __hip_bfloat16* __restrict__ A, int lda,
    const __hip_bfloat16* __restrict__ BT, int ldb,
    float* __restrict__ C, int ldc, int ntiles,
    const float* __restrict__ bias)
{
    const int W  = xcd_remap();
    const int bx = W % gridDim.x;
    const int by = W / gridDim.x;
    gemm8p_body(A, lda, BT, ldb, C, ldc, ntiles, bias, by * BM, bx * BN);
}

// Split-K=4: z selects K quarter and output buffer (summed in final_out).
// Grid 4 x 16 x 4 = 256 blocks -> exact machine fill at 1 block/CU.
__global__ __launch_bounds__(512) void gemm8p_splitk4(
    const __hip_bfloat16* __restrict__ A, int lda,
    const __hip_bfloat16* __restrict__ BT, int ldb,
    float* __restrict__ C0, float* __restrict__ C1,
    float* __restrict__ C2, float* __restrict__ C3,
    int ldc, int kq_tiles)
{
    const int W   = xcd_remap();
    const int gxy = gridDim.x * gridDim.y;
    const int z   = W / gxy;
    const int rem = W % gxy;
    const int bx  = rem % gridDim.x;
    const int by  = rem / gridDim.x;
    float* C = (z == 0) ? C0 : (z == 1) ? C1 : (z == 2) ? C2 : C3;
    gemm8p_body(A + (size_t)z * kq_tiles * 64, lda,
                BT + (size_t)z * kq_tiles * 64, ldb,
                C, ldc, kq_tiles, nullptr,
                by * BM, bx * BN);
}

// ---------------------------------------------------------------------------
// Fused flat prep: 4 weight casts + x-last cast + 2 bias concats, one launch.
// ---------------------------------------------------------------------------
#define WG ((CC*CHIN)/4)       // 524288
#define XG ((BB*CHIN)/4)       // 2097152
#define PREP_BLOCKS ((4*WG + XG + 1024) / 256)   // 16388

__device__ __forceinline__ void store_bf4(__hip_bfloat16* dst, float4 vv) {
    union { __hip_bfloat16 h[4]; unsigned long long u; } pk;
    pk.h[0] = (__hip_bfloat16)vv.x; pk.h[1] = (__hip_bfloat16)vv.y;
    pk.h[2] = (__hip_bfloat16)vv.z; pk.h[3] = (__hip_bfloat16)vv.w;
    *(unsigned long long*)dst = pk.u;
}

__global__ __launch_bounds__(256) void prep_flat(
    const float* __restrict__ Wk, const float* __restrict__ Wv,
    const float* __restrict__ WEk, const float* __restrict__ WEv,
    const float* __restrict__ x,
    const float* __restrict__ bk, const float* __restrict__ bv,
    const float* __restrict__ bEk, const float* __restrict__ bEv,
    __hip_bfloat16* __restrict__ Wkvb, __hip_bfloat16* __restrict__ WEkvb,
    __hip_bfloat16* __restrict__ xb,
    float* __restrict__ bkv, float* __restrict__ bEkv)
{
    const int gidx = blockIdx.x * 256 + threadIdx.x;
    if (gidx < 4 * WG) {
        const int mat = gidx >> 19;
        const int off = (gidx & (WG - 1)) * 4;
        const float* src = (mat == 0) ? Wk : (mat == 1) ? Wv : (mat == 2) ? WEk : WEv;
        __hip_bfloat16* dst = (mat < 2) ? (Wkvb + (size_t)mat * (CC * CHIN))
                                        : (WEkvb + (size_t)(mat - 2) * (CC * CHIN));
        store_bf4(dst + off, *(const float4*)(src + off));
    } else if (gidx < 4 * WG + XG) {
        const int off = (gidx - 4 * WG) * 4;
        const int b = off >> 11;
        const int i = off & (CHIN - 1);
        store_bf4(xb + off, *(const float4*)(x + ((size_t)b * TT + TT - 1) * CHIN + i));
    } else {
        const int off = (gidx - 4 * WG - XG) * 4;
        #pragma unroll
        for (int e = 0; e < 4; ++e) {
            const int t = off + e;
            if (t < 2 * CC) bkv[t]  = (t < CC) ? bk[t] : bv[t - CC];
            else { const int u2 = t - 2 * CC; bEkv[u2] = (u2 < CC) ? bEk[u2] : bEv[u2 - CC]; }
        }
    }
}

// static[k][i][n] (fp32) -> staticT[k*NN+n][i] (bf16)
__global__ void transpose_static(const float* __restrict__ st,
                                 __hip_bfloat16* __restrict__ stT)
{
    __shared__ float tile[32][33];
    const int k  = blockIdx.z;
    const int i0 = blockIdx.x * 32;
    const int n0 = blockIdx.y * 32;
    const int tx = threadIdx.x, ty = threadIdx.y;   // 32 x 8
    #pragma unroll
    for (int r = 0; r < 32; r += 8)
        tile[ty + r][tx] = st[((size_t)k * CHIN + i0 + ty + r) * NN + n0 + tx];
    __syncthreads();
    #pragma unroll
    for (int r = 0; r < 32; r += 8)
        stT[((size_t)k * NN + n0 + ty + r) * CHIN + i0 + tx] = (__hip_bfloat16)tile[tx][ty + r];
}

// Ev transpose straight from fp32 Ekv (cols CC..2CC): EvC[c][kn] = bf16(Ekv[kn][CC+c])
__global__ void transpose_Ev(const float* __restrict__ Ekv,
                             __hip_bfloat16* __restrict__ EvC)
{
    __shared__ float tile[32][33];
    const int c0  = blockIdx.x * 32;
    const int kn0 = blockIdx.y * 32;
    const int tx = threadIdx.x, ty = threadIdx.y;   // 32 x 8
    #pragma unroll
    for (int r = 0; r < 32; r += 8)
        tile[ty + r][tx] = Ekv[(size_t)(kn0 + ty + r) * (2 * CC) + CC + c0 + tx];
    __syncthreads();
    #pragma unroll
    for (int r = 0; r < 32; r += 8)
        EvC[(size_t)(c0 + ty + r) * KN + kn0 + tx] = (__hip_bfloat16)tile[tx][ty + r];
}

// Merged per-kn-row pass over Ekv, single read: EknT = normalized Ek (bf16); g = Ww.Ev
// 256 threads x float4 covers CC=1024 exactly; Ek row stashed in registers.
__global__ __launch_bounds__(256) void norm_prep_E(const float* __restrict__ Ekv,
                                                   const float* __restrict__ Ww,
                                                   __hip_bfloat16* __restrict__ EknT,
                                                   float* __restrict__ g)
{
    const int kn = blockIdx.x;
    const int t  = threadIdx.x;
    const float* pk = Ekv + (size_t)kn * (2 * CC);
    const float4 ek = ((const float4*)pk)[t];
    const float4 ev = ((const float4*)(pk + CC))[t];
    const float4 ww = ((const float4*)Ww)[t];
    float s2 = ek.x*ek.x + ek.y*ek.y + ek.z*ek.z + ek.w*ek.w;
    float sg = ww.x*ev.x + ww.y*ev.y + ww.z*ev.z + ww.w*ev.w;
    #pragma unroll
    for (int o = 32; o > 0; o >>= 1) { s2 += __shfl_down(s2, o, 64); sg += __shfl_down(sg, o, 64); }
    __shared__ float r2[4], rg[4];
    if ((t & 63) == 0) { r2[t >> 6] = s2; rg[t >> 6] = sg; }
    __syncthreads();
    const float tot = r2[0] + r2[1] + r2[2] + r2[3];
    const float inv = 1.f / fmaxf(sqrtf(tot), 1e-8f);
    store_bf4(EknT + (size_t)kn * CC + t * 4,
              make_float4(ek.x * inv, ek.y * inv, ek.z * inv, ek.w * inv));
    if (t == 0) g[kn] = rg[0] + rg[1] + rg[2] + rg[3];
}

// Single-read L2-normalize: row of kv (first CC cols) -> bf16 kn row.
__global__ __launch_bounds__(256) void rownorm(const float* __restrict__ in, int in_ld,
                                               __hip_bfloat16* __restrict__ out)
{
    const int row = blockIdx.x;
    const int t   = threadIdx.x;
    const float4 v = ((const float4*)(in + (size_t)row * in_ld))[t];
    float s = v.x*v.x + v.y*v.y + v.z*v.z + v.w*v.w;
    #pragma unroll
    for (int o = 32; o > 0; o >>= 1) s += __shfl_down(s, o, 64);
    __shared__ float red[4];
    if ((t & 63) == 0) red[t >> 6] = s;
    __syncthreads();
    const float tot = red[0] + red[1] + red[2] + red[3];
    const float inv = 1.f / fmaxf(sqrtf(tot), 1e-8f);
    store_bf4(out + (size_t)row * CC + t * 4,
              make_float4(v.x * inv, v.y * inv, v.z * inv, v.w * inv));
}

// per (b,k): softmax over 512, fw = sigmoid(dot(w,g)+bw), u = w*fw (bf16).
// 4 waves/block, 16B/lane loads (lane owns 8 contiguous elems; reductions are
// permutation-invariant so the remap is free).
__global__ __launch_bounds__(256) void softmax_u(const float* __restrict__ sim,
                                                 const float* __restrict__ g,
                                                 const float* __restrict__ bw,
                                                 __hip_bfloat16* __restrict__ u)
{
    const int bk = blockIdx.x * 4 + (threadIdx.x >> 6);
    const int b = bk / KK, k = bk % KK;
    const float* sp = sim + (size_t)b * KN + k * NN;
    const float* gp = g + k * NN;
    const int lane = threadIdx.x & 63;

    const float4 v0 = ((const float4*)sp)[lane * 2];
    const float4 v1 = ((const float4*)sp)[lane * 2 + 1];
    float vals[8] = {v0.x, v0.y, v0.z, v0.w, v1.x, v1.y, v1.z, v1.w};
    float m = -1e30f;
    #pragma unroll
    for (int j = 0; j < 8; ++j) m = fmaxf(m, vals[j]);
    #pragma unroll
    for (int o = 32; o > 0; o >>= 1) m = fmaxf(m, __shfl_xor(m, o, 64));
    float sum = 0.f;
    #pragma unroll
    for (int j = 0; j < 8; ++j) { vals[j] = expf(vals[j] - m); sum += vals[j]; }
    #pragma unroll
    for (int o = 32; o > 0; o >>= 1) sum += __shfl_xor(sum, o, 64);
    const float inv = 1.f / sum;
    const float4 g0 = ((const float4*)gp)[lane * 2];
    const float4 g1 = ((const float4*)gp)[lane * 2 + 1];
    const float gv[8] = {g0.x, g0.y, g0.z, g0.w, g1.x, g1.y, g1.z, g1.w};
    float dot = 0.f;
    #pragma unroll
    for (int j = 0; j < 8; ++j) { vals[j] *= inv; dot += vals[j] * gv[j]; }
    #pragma unroll
    for (int o = 32; o > 0; o >>= 1) dot += __shfl_xor(dot, o, 64);
    const float fw = 1.f / (1.f + expf(-(dot + bw[0])));
    union { __hip_bfloat16 h[8]; bf16x8 v; } pk;
    #pragma unroll
    for (int j = 0; j < 8; ++j) pk.h[j] = (__hip_bfloat16)(vals[j] * fw);
    *(bf16x8*)(u + (size_t)b * KN + k * NN + lane * 8) = pk.v;
}

// out[b][kk] = bout[kk] + sum_c Wout[kk][c]*relu(v[c]) + Wout[kk][CC+c]*relu(sum fE_z[c])
// 256 threads x float4 covers CC exactly: loop-free body.
__global__ __launch_bounds__(256) void final_out(const float* __restrict__ kv,
                                                 const float* __restrict__ fE0,
                                                 const float* __restrict__ fE1,
                                                 const float* __restrict__ fE2,
                                                 const float* __restrict__ fE3,
                                                 const float* __restrict__ Wout,
                                                 const float* __restrict__ bout,
                                                 float* __restrict__ out)
{
    const int b = blockIdx.x;
    const int t = threadIdx.x;
    const float4 v4 = ((const float4*)(kv + (size_t)b * (2 * CC) + CC))[t];
    const float4 a0 = ((const float4*)(fE0 + (size_t)b * CC))[t];
    const float4 a1 = ((const float4*)(fE1 + (size_t)b * CC))[t];
    const float4 a2 = ((const float4*)(fE2 + (size_t)b * CC))[t];
    const float4 a3 = ((const float4*)(fE3 + (size_t)b * CC))[t];
    const float rv[4] = {fmaxf(v4.x, 0.f), fmaxf(v4.y, 0.f), fmaxf(v4.z, 0.f), fmaxf(v4.w, 0.f)};
    const float rf[4] = {fmaxf(a0.x + a1.x + a2.x + a3.x, 0.f),
                         fmaxf(a0.y + a1.y + a2.y + a3.y, 0.f),
                         fmaxf(a0.z + a1.z + a2.z + a3.z, 0.f),
                         fmaxf(a0.w + a1.w + a2.w + a3.w, 0.f)};
    float acc[KK];
    #pragma unroll
    for (int kk = 0; kk < KK; ++kk) {
        const float4 wv = ((const float4*)(Wout + (size_t)kk * 2 * CC))[t];
        const float4 wf = ((const float4*)(Wout + (size_t)kk * 2 * CC + CC))[t];
        acc[kk] = wv.x * rv[0] + wv.y * rv[1] + wv.z * rv[2] + wv.w * rv[3]
                + wf.x * rf[0] + wf.y * rf[1] + wf.z * rf[2] + wf.w * rf[3];
    }
    __shared__ float red[KK][4];
    const int lane = t & 63, wave = t >> 6;
    #pragma unroll
    for (int kk = 0; kk < KK; ++kk) {
        float s = acc[kk];
        #pragma unroll
        for (int o = 32; o > 0; o >>= 1) s += __shfl_down(s, o, 64);
        if (lane == 0) red[kk][wave] = s;
    }
    __syncthreads();
    if (t < KK) {
        float s = red[t][0] + red[t][1] + red[t][2] + red[t][3];
        out[(size_t)b * KK + t] = s + bout[t];
    }
}

extern "C" void kernel_launch(void* const* d_in, const int* in_sizes, int n_in,
                              void* d_out, int out_size, void* d_ws, size_t ws_size,
                              hipStream_t stream)
{
    const float* x    = (const float*)d_in[0];
    const float* stat = (const float*)d_in[1];
    const float* Wk   = (const float*)d_in[2];
    const float* bk   = (const float*)d_in[3];
    const float* Wv   = (const float*)d_in[4];
    const float* bv   = (const float*)d_in[5];
    const float* WEk  = (const float*)d_in[6];
    const float* bEk  = (const float*)d_in[7];
    const float* WEv  = (const float*)d_in[8];
    const float* bEv  = (const float*)d_in[9];
    const float* Ww   = (const float*)d_in[10];
    const float* bw   = (const float*)d_in[11];
    const float* Wout = (const float*)d_in[12];
    const float* bout = (const float*)d_in[13];
    float* out = (float*)d_out;
    char* ws = (char*)d_ws;

    __hip_bfloat16* xb      = (__hip_bfloat16*)(ws + 0);          // [BB][CHIN]    16.78 MB
    __hip_bfloat16* Wkvb    = (__hip_bfloat16*)(ws + 16777216);   // [2CC][CHIN]    8.39 MB
    __hip_bfloat16* WEkvb   = (__hip_bfloat16*)(ws + 25165824);   // [2CC][CHIN]    8.39 MB
    __hip_bfloat16* staticT = (__hip_bfloat16*)(ws + 33554432);   // [KN][CHIN]    10.49 MB
    float*          Ekv     = (float*)(ws + 44040192);            // [KN][2CC]     20.97 MB
    __hip_bfloat16* EknT    = (__hip_bfloat16*)(ws + 65011712);   // [KN][CC]       5.24 MB
    __hip_bfloat16* EvC     = (__hip_bfloat16*)(ws + 75497472);   // [CC][KN]       5.24 MB
    float*          g       = (float*)(ws + 80740352);            // [KN]           10 KB
    float*          kv      = (float*)(ws + 80750592);            // [BB][2CC]     33.55 MB
    __hip_bfloat16* kn      = (__hip_bfloat16*)(ws + 114305024);  // [BB][CC]       8.39 MB
    float*          sim     = (float*)(ws + 122693632);           // [BB][KN]      41.94 MB
    __hip_bfloat16* u       = (__hip_bfloat16*)(ws + 164636672);  // [BB][KN]      20.97 MB
    float*          fE      = (float*)(ws + 185608192);           // [BB][CC]      16.78 MB
    float*          bkv     = (float*)(ws + 202385408);           // [2CC]          8 KB
    float*          bEkv    = (float*)(ws + 202393600);           // [2CC]          8 KB
    float*          fE2     = (float*)(ws + 202401792);           // [BB][CC]      16.78 MB
    float*          fE3     = (float*)(ws + 219179008);           // [BB][CC]      16.78 MB
    float*          fE4     = (float*)(ws + 235956224);           // [BB][CC]      16.78 MB

    // 0. all flat prep in one launch + static transpose
    prep_flat<<<PREP_BLOCKS, 256, 0, stream>>>(
        Wk, Wv, WEk, WEv, x, bk, bv, bEk, bEv, Wkvb, WEkvb, xb, bkv, bEkv);
    transpose_static<<<dim3(CHIN / 32, NN / 32, KK), dim3(32, 8), 0, stream>>>(stat, staticT);

    // 1+5. Fused: Ekv (M=KN) + kv (M=BB); N=2CC, K=CHIN. Grid (8, 26) = 208.
    gemm8p_dual<<<dim3(2 * CC / BN, KN / BM + BB / BM), 512, 0, stream>>>(
        staticT, WEkvb, Ekv, bEkv, KN / BM,
        xb, Wkvb, kv, bkv);
    // 2+3. Ek row-norm + g, single pass
    norm_prep_E<<<KN, 256, 0, stream>>>(Ekv, Ww, EknT, g);
    // 4. EvC[c][kn] = bf16(Ekv[kn][CC+c])
    transpose_Ev<<<dim3(CC / 32, KN / 32), dim3(32, 8), 0, stream>>>(Ekv, EvC);
    // 6. kn = rownormalize(k_pre), single pass
    rownorm<<<BB, 256, 0, stream>>>(kv, 2 * CC, kn);
    // 7. sim = kn @ EknT^T  (M=BB, N=KN, K=CC). Grid (10, 16) = 160.
    gemm8p<<<dim3(KN / BN, BB / BM), 512, 0, stream>>>(
        kn, CC, EknT, CC, sim, KN, CC / 64, nullptr);
    // 8. softmax + fw -> u (bf16)
    softmax_u<<<BB * KK / 4, 256, 0, stream>>>(sim, g, bw, u);
    // 9. fE partials = u @ EvC^T  (M=BB, N=CC, K=KN, split-K=4). Grid 4x16x4 = 256.
    gemm8p_splitk4<<<dim3(CC / BN, BB / BM, 4), 512, 0, stream>>>(
        u, KN, EvC, KN, fE, fE2, fE3, fE4, CC, (KN / 4) / 64);
    // 10. out = relu([v, sum fE_z]) @ Wout^T + bout (fp32 out)
    final_out<<<BB, 256, 0, stream>>>(kv, fE, fE2, fE3, fE4, Wout, bout, out);
}

// Round 5
// 521.055 us; speedup vs baseline: 1.2088x; 1.0142x over previous
//
#include <hip/hip_runtime.h>
#include <hip/hip_bf16.h>

// Problem constants
#define BB 4096
#define TT 8
#define CHIN 2048
#define CC 1024
#define NN 512
#define KK 5
#define KN (KK*NN)   // 2560

typedef __bf16 bf16x8 __attribute__((ext_vector_type(8)));
typedef float  f32x4  __attribute__((ext_vector_type(4)));

// ---------------------------------------------------------------------------
// 256x256 8-wave GEMM (C = A * B^T + bias_col), bf16 in fp32 out.
// T2 LDS XOR swizzle + T3/T4 counted-vmcnt (2-tile-deep prefetch) + T5 setprio
// + T1 XCD chunk swizzle.  (Verified since round 3.)
// ---------------------------------------------------------------------------
#define BM 256
#define BN 256

__device__ __forceinline__ void gload_lds16(const __hip_bfloat16* g, __hip_bfloat16* l) {
    __builtin_amdgcn_global_load_lds(
        (__attribute__((address_space(1))) void*)const_cast<__hip_bfloat16*>(g),
        (__attribute__((address_space(3))) void*)l, 16, 0, 0);
}

// Stage one (threads*16B) chunk of a row-major half-tile into LDS at l.
// LDS dest is LINEAR; read-side XOR swizzle pre-applied to the GLOBAL source.
__device__ __forceinline__ void stage_q(const __hip_bfloat16* __restrict__ g, int ldg,
                                        __hip_bfloat16* l, int tid)
{
    const int P   = tid * 16;                      // linear LDS byte offset
    const int row = P >> 7;                        // 128 B per row
    const int bc  = (P & 127) ^ ((row & 7) << 4);  // inverse swizzle on source
    gload_lds16(g + (size_t)row * ldg + (bc >> 1),
                (__hip_bfloat16*)((char*)l + P));
}

__device__ __forceinline__ int xcd_remap()
{
    const int gx = gridDim.x, gy = gridDim.y, gz = gridDim.z;
    const int lin = blockIdx.x + gx * (blockIdx.y + gy * blockIdx.z);
    const int nwg = gx * gy * gz;
    return (lin & 7) * (nwg >> 3) + (lin >> 3);
}

__device__ __forceinline__ void gemm8p_body(
    const __hip_bfloat16* __restrict__ Ag, int lda,
    const __hip_bfloat16* __restrict__ Bg, int ldb,
    float* __restrict__ Cmat, int ldc,
    int ntiles,                         // K / 64  (>= 2 here)
    const float* __restrict__ bias_col,
    int bm, int bn)
{
    __shared__ __align__(16) __hip_bfloat16 As[2][BM * 64];   // 64 KiB
    __shared__ __align__(16) __hip_bfloat16 Bs[2][BN * 64];   // 64 KiB

    const int tid  = threadIdx.x;
    const int wave = tid >> 6;
    const int lane = tid & 63;
    const int wrow = (wave >> 2) * 128;   // 2 waves in M
    const int wcol = (wave & 3) * 64;     // 4 waves in N
    const int fr   = lane & 15;
    const int kb0  = (lane >> 4) * 16;    // quad k-byte offset

    const __hip_bfloat16* Arow = Ag + (size_t)bm * lda;
    const __hip_bfloat16* Brow = Bg + (size_t)bn * ldb;

    const int rA = wrow + fr, rB = wcol + fr;
    const int swA = (rA & 7) << 4, swB = (rB & 7) << 4;
    const int offA0 = rA * 128 + ((kb0     ) ^ swA);
    const int offA1 = rA * 128 + ((kb0 + 64) ^ swA);
    const int offB0 = rB * 128 + ((kb0     ) ^ swB);
    const int offB1 = rB * 128 + ((kb0 + 64) ^ swB);

    f32x4 acc[8][4];
    #pragma unroll
    for (int i = 0; i < 8; ++i)
        #pragma unroll
        for (int j = 0; j < 4; ++j)
            acc[i][j] = {0.f, 0.f, 0.f, 0.f};

    bf16x8 a[4][2];
    bf16x8 b01[2][2];
    bf16x8 b23[2][2];

    #pragma unroll
    for (int q = 0; q < 4; ++q)
        stage_q(Arow + (size_t)(64 * q) * lda, lda, &As[0][q * 4096], tid);
    #pragma unroll
    for (int q = 0; q < 4; ++q)
        stage_q(Brow + (size_t)(64 * q) * ldb, ldb, &Bs[0][q * 4096], tid);
    if (ntiles > 1) {
        #pragma unroll
        for (int q = 0; q < 4; ++q)
            stage_q(Arow + (size_t)(64 * q) * lda + 64, lda, &As[1][q * 4096], tid);
        #pragma unroll
        for (int q = 0; q < 4; ++q)
            stage_q(Brow + (size_t)(64 * q) * ldb + 64, ldb, &Bs[1][q * 4096], tid);
        asm volatile("s_waitcnt vmcnt(8)" ::: "memory");
    } else {
        asm volatile("s_waitcnt vmcnt(0)" ::: "memory");
    }
    __builtin_amdgcn_s_barrier();
    __builtin_amdgcn_sched_barrier(0);

    for (int T = 0; T < ntiles; ++T) {
        const char* aB = (const char*)&As[T & 1][0];
        const char* bB = (const char*)&Bs[T & 1][0];
        const char* aK0 = aB + offA0; const char* aK1 = aB + offA1;
        const char* bK0 = bB + offB0; const char* bK1 = bB + offB1;
        const bool pf = (T + 2 < ntiles);
        const int  kc = (T + 2) * 64;

        // ---- P0
        #pragma unroll
        for (int i = 0; i < 4; ++i) {
            a[i][0] = *(const bf16x8*)(aK0 + i * 2048);
            a[i][1] = *(const bf16x8*)(aK1 + i * 2048);
        }
        #pragma unroll
        for (int j = 0; j < 2; ++j) {
            b01[j][0] = *(const bf16x8*)(bK0 + j * 2048);
            b01[j][1] = *(const bf16x8*)(bK1 + j * 2048);
        }
        __builtin_amdgcn_s_barrier();
        asm volatile("s_waitcnt lgkmcnt(0)" ::: "memory");
        __builtin_amdgcn_sched_barrier(0);
        __builtin_amdgcn_s_setprio(1);
        #pragma unroll
        for (int i = 0; i < 4; ++i)
            #pragma unroll
            for (int j = 0; j < 2; ++j)
                #pragma unroll
                for (int k2 = 0; k2 < 2; ++k2)
                    acc[i][j] = __builtin_amdgcn_mfma_f32_16x16x32_bf16(
                        a[i][k2], b01[j][k2], acc[i][j], 0, 0, 0);
        __builtin_amdgcn_s_setprio(0);
        __builtin_amdgcn_s_barrier();
        __builtin_amdgcn_sched_barrier(0);

        // ---- P1
        #pragma unroll
        for (int j = 0; j < 2; ++j) {
            b23[j][0] = *(const bf16x8*)(bK0 + (j + 2) * 2048);
            b23[j][1] = *(const bf16x8*)(bK1 + (j + 2) * 2048);
        }
        if (pf) {
            stage_q(Arow + kc,                       lda, &As[T & 1][0],        tid);
            stage_q(Arow + (size_t)128 * lda + kc,   lda, &As[T & 1][2 * 4096], tid);
        }
        __builtin_amdgcn_s_barrier();
        asm volatile("s_waitcnt lgkmcnt(0)" ::: "memory");
        __builtin_amdgcn_sched_barrier(0);
        __builtin_amdgcn_s_setprio(1);
        #pragma unroll
        for (int i = 0; i < 4; ++i)
            #pragma unroll
            for (int j = 0; j < 2; ++j)
                #pragma unroll
                for (int k2 = 0; k2 < 2; ++k2)
                    acc[i][j + 2] = __builtin_amdgcn_mfma_f32_16x16x32_bf16(
                        a[i][k2], b23[j][k2], acc[i][j + 2], 0, 0, 0);
        __builtin_amdgcn_s_setprio(0);
        __builtin_amdgcn_s_barrier();
        __builtin_amdgcn_sched_barrier(0);

        // ---- P2
        #pragma unroll
        for (int i = 0; i < 4; ++i) {
            a[i][0] = *(const bf16x8*)(aK0 + 8192 + i * 2048);
            a[i][1] = *(const bf16x8*)(aK1 + 8192 + i * 2048);
        }
        if (pf) {
            #pragma unroll
            for (int q = 0; q < 4; ++q)
                stage_q(Brow + (size_t)(64 * q) * ldb + kc, ldb, &Bs[T & 1][q * 4096], tid);
        }
        __builtin_amdgcn_s_barrier();
        asm volatile("s_waitcnt lgkmcnt(0)" ::: "memory");
        __builtin_amdgcn_sched_barrier(0);
        __builtin_amdgcn_s_setprio(1);
        #pragma unroll
        for (int i = 0; i < 4; ++i)
            #pragma unroll
            for (int j = 0; j < 2; ++j)
                #pragma unroll
                for (int k2 = 0; k2 < 2; ++k2)
                    acc[i + 4][j + 2] = __builtin_amdgcn_mfma_f32_16x16x32_bf16(
                        a[i][k2], b23[j][k2], acc[i + 4][j + 2], 0, 0, 0);
        __builtin_amdgcn_s_setprio(0);
        __builtin_amdgcn_s_barrier();
        __builtin_amdgcn_sched_barrier(0);

        // ---- P3
        if (pf) {
            stage_q(Arow + (size_t)64 * lda + kc,    lda, &As[T & 1][4096],     tid);
            stage_q(Arow + (size_t)192 * lda + kc,   lda, &As[T & 1][3 * 4096], tid);
            asm volatile("s_waitcnt vmcnt(8)" ::: "memory");
        } else if (T + 1 < ntiles) {
            asm volatile("s_waitcnt vmcnt(0)" ::: "memory");
        }
        __builtin_amdgcn_s_barrier();
        __builtin_amdgcn_sched_barrier(0);
        __builtin_amdgcn_s_setprio(1);
        #pragma unroll
        for (int i = 0; i < 4; ++i)
            #pragma unroll
            for (int j = 0; j < 2; ++j)
                #pragma unroll
                for (int k2 = 0; k2 < 2; ++k2)
                    acc[i + 4][j] = __builtin_amdgcn_mfma_f32_16x16x32_bf16(
                        a[i][k2], b01[j][k2], acc[i + 4][j], 0, 0, 0);
        __builtin_amdgcn_s_setprio(0);
        __builtin_amdgcn_s_barrier();
        __builtin_amdgcn_sched_barrier(0);
    }

    const int quad = lane >> 4;
    #pragma unroll
    for (int i = 0; i < 8; ++i) {
        #pragma unroll
        for (int j = 0; j < 4; ++j) {
            const int col = bn + wcol + j * 16 + fr;
            const float bc = bias_col ? bias_col[col] : 0.f;
            #pragma unroll
            for (int r = 0; r < 4; ++r) {
                const int row = bm + wrow + i * 16 + quad * 4 + r;
                Cmat[(size_t)row * ldc + col] = acc[i][j][r] + bc;
            }
        }
    }
}

__global__ __launch_bounds__(512) void gemm8p_dual(
    const __hip_bfloat16* __restrict__ A0, const __hip_bfloat16* __restrict__ B0,
    float* __restrict__ C0, const float* __restrict__ bias0, int mt0,
    const __hip_bfloat16* __restrict__ A1, const __hip_bfloat16* __restrict__ B1,
    float* __restrict__ C1, const float* __restrict__ bias1)
{
    const int W  = xcd_remap();
    const int bx = W % gridDim.x;
    const int by = W / gridDim.x;
    const bool s = by >= mt0;
    gemm8p_body(s ? A1 : A0, CHIN, s ? B1 : B0, CHIN,
                s ? C1 : C0, 2 * CC, CHIN / 64,
                s ? bias1 : bias0,
                (s ? by - mt0 : by) * BM, bx * BN);
}

__global__ __launch_bounds__(512) void gemm8p(
    const __hip_bfloat16* __restrict__ A, int lda,
    const __hip_bfloat16* __restrict__ BT, int ldb,
    float* __restrict__ C, int ldc, int ntiles,
    const float* __restrict__ bias)
{
    const int W  = xcd_remap();
    const int bx = W % gridDim.x;
    const int by = W / gridDim.x;
    gemm8p_body(A, lda, BT, ldb, C, ldc, ntiles, bias, by * BM, bx * BN);
}

// ---------------------------------------------------------------------------
// 128x128 4-wave variant of the SAME 4-phase schedule, split-K=2.
// Grid (8, 32, 2) = 512 blocks = 2 blocks/CU (64 KiB LDS each) -> 2 waves/SIMD.
// Stage unit = 32 rows x 64 cols = 4 KiB (256 thr x 16 B); 8 loads/tile ->
// identical vmcnt(8) invariant. Region liveness: A-low (u0,u2) staged P1,
// B (u0..u3) staged P2, A-high (u1,u3) staged P3 — each after its last read.
// ---------------------------------------------------------------------------
__global__ __launch_bounds__(256) void gemm128_splitk2(
    const __hip_bfloat16* __restrict__ A, int lda,
    const __hip_bfloat16* __restrict__ BT, int ldb,
    float* __restrict__ C0, float* __restrict__ C1, int ldc, int khalf_tiles)
{
    __shared__ __align__(16) __hip_bfloat16 As[2][128 * 64];   // 32 KiB
    __shared__ __align__(16) __hip_bfloat16 Bs[2][128 * 64];   // 32 KiB

    const int W   = xcd_remap();
    const int gxy = gridDim.x * gridDim.y;
    const int z   = W / gxy;
    const int rem = W % gxy;
    const int bx  = rem % gridDim.x;
    const int by  = rem / gridDim.x;
    const int bm = by * 128, bn = bx * 128;
    const int ntiles = khalf_tiles;

    const __hip_bfloat16* Ag = A  + (size_t)z * khalf_tiles * 64;
    const __hip_bfloat16* Bg = BT + (size_t)z * khalf_tiles * 64;
    float* Cmat = z ? C1 : C0;

    const int tid  = threadIdx.x;
    const int wave = tid >> 6;
    const int lane = tid & 63;
    const int wrow = (wave >> 1) * 64;    // 2 waves in M
    const int wcol = (wave & 1) * 64;     // 2 waves in N
    const int fr   = lane & 15;
    const int kb0  = (lane >> 4) * 16;

    const __hip_bfloat16* Arow = Ag + (size_t)bm * lda;
    const __hip_bfloat16* Brow = Bg + (size_t)bn * ldb;

    const int rA = wrow + fr, rB = wcol + fr;
    const int swA = (rA & 7) << 4, swB = (rB & 7) << 4;
    const int offA0 = rA * 128 + ((kb0     ) ^ swA);
    const int offA1 = rA * 128 + ((kb0 + 64) ^ swA);
    const int offB0 = rB * 128 + ((kb0     ) ^ swB);
    const int offB1 = rB * 128 + ((kb0 + 64) ^ swB);

    f32x4 acc[4][4];
    #pragma unroll
    for (int i = 0; i < 4; ++i)
        #pragma unroll
        for (int j = 0; j < 4; ++j)
            acc[i][j] = {0.f, 0.f, 0.f, 0.f};

    bf16x8 a[2][2];
    bf16x8 b01[2][2];
    bf16x8 b23[2][2];

    // Prologue: tiles 0 and 1 fully (8 unit-loads each).
    #pragma unroll
    for (int q = 0; q < 4; ++q)
        stage_q(Arow + (size_t)(32 * q) * lda, lda, &As[0][q * 2048], tid);
    #pragma unroll
    for (int q = 0; q < 4; ++q)
        stage_q(Brow + (size_t)(32 * q) * ldb, ldb, &Bs[0][q * 2048], tid);
    #pragma unroll
    for (int q = 0; q < 4; ++q)
        stage_q(Arow + (size_t)(32 * q) * lda + 64, lda, &As[1][q * 2048], tid);
    #pragma unroll
    for (int q = 0; q < 4; ++q)
        stage_q(Brow + (size_t)(32 * q) * ldb + 64, ldb, &Bs[1][q * 2048], tid);
    asm volatile("s_waitcnt vmcnt(8)" ::: "memory");
    __builtin_amdgcn_s_barrier();
    __builtin_amdgcn_sched_barrier(0);

    for (int T = 0; T < ntiles; ++T) {
        const char* aB = (const char*)&As[T & 1][0];
        const char* bB = (const char*)&Bs[T & 1][0];
        const char* aK0 = aB + offA0; const char* aK1 = aB + offA1;
        const char* bK0 = bB + offB0; const char* bK1 = bB + offB1;
        const bool pf = (T + 2 < ntiles);
        const int  kc = (T + 2) * 64;

        // ---- P0: read a-low (i0-1) + b01; MFMA (i01 x j01)
        #pragma unroll
        for (int i = 0; i < 2; ++i) {
            a[i][0] = *(const bf16x8*)(aK0 + i * 2048);
            a[i][1] = *(const bf16x8*)(aK1 + i * 2048);
        }
        #pragma unroll
        for (int j = 0; j < 2; ++j) {
            b01[j][0] = *(const bf16x8*)(bK0 + j * 2048);
            b01[j][1] = *(const bf16x8*)(bK1 + j * 2048);
        }
        __builtin_amdgcn_s_barrier();
        asm volatile("s_waitcnt lgkmcnt(0)" ::: "memory");
        __builtin_amdgcn_sched_barrier(0);
        __builtin_amdgcn_s_setprio(1);
        #pragma unroll
        for (int i = 0; i < 2; ++i)
            #pragma unroll
            for (int j = 0; j < 2; ++j)
                #pragma unroll
                for (int k2 = 0; k2 < 2; ++k2)
                    acc[i][j] = __builtin_amdgcn_mfma_f32_16x16x32_bf16(
                        a[i][k2], b01[j][k2], acc[i][j], 0, 0, 0);
        __builtin_amdgcn_s_setprio(0);
        __builtin_amdgcn_s_barrier();
        __builtin_amdgcn_sched_barrier(0);

        // ---- P1: read b23; stage A u0 (rows 0-31), u2 (rows 64-95); MFMA (i01 x j23)
        #pragma unroll
        for (int j = 0; j < 2; ++j) {
            b23[j][0] = *(const bf16x8*)(bK0 + (j + 2) * 2048);
            b23[j][1] = *(const bf16x8*)(bK1 + (j + 2) * 2048);
        }
        if (pf) {
            stage_q(Arow + kc,                      lda, &As[T & 1][0],        tid);
            stage_q(Arow + (size_t)64 * lda + kc,   lda, &As[T & 1][2 * 2048], tid);
        }
        __builtin_amdgcn_s_barrier();
        asm volatile("s_waitcnt lgkmcnt(0)" ::: "memory");
        __builtin_amdgcn_sched_barrier(0);
        __builtin_amdgcn_s_setprio(1);
        #pragma unroll
        for (int i = 0; i < 2; ++i)
            #pragma unroll
            for (int j = 0; j < 2; ++j)
                #pragma unroll
                for (int k2 = 0; k2 < 2; ++k2)
                    acc[i][j + 2] = __builtin_amdgcn_mfma_f32_16x16x32_bf16(
                        a[i][k2], b23[j][k2], acc[i][j + 2], 0, 0, 0);
        __builtin_amdgcn_s_setprio(0);
        __builtin_amdgcn_s_barrier();
        __builtin_amdgcn_sched_barrier(0);

        // ---- P2: read a-high (i2-3); stage B u0..u3; MFMA (i23 x j23)
        #pragma unroll
        for (int i = 0; i < 2; ++i) {
            a[i][0] = *(const bf16x8*)(aK0 + 4096 + i * 2048);
            a[i][1] = *(const bf16x8*)(aK1 + 4096 + i * 2048);
        }
        if (pf) {
            #pragma unroll
            for (int q = 0; q < 4; ++q)
                stage_q(Brow + (size_t)(32 * q) * ldb + kc, ldb, &Bs[T & 1][q * 2048], tid);
        }
        __builtin_amdgcn_s_barrier();
        asm volatile("s_waitcnt lgkmcnt(0)" ::: "memory");
        __builtin_amdgcn_sched_barrier(0);
        __builtin_amdgcn_s_setprio(1);
        #pragma unroll
        for (int i = 0; i < 2; ++i)
            #pragma unroll
            for (int j = 0; j < 2; ++j)
                #pragma unroll
                for (int k2 = 0; k2 < 2; ++k2)
                    acc[i + 2][j + 2] = __builtin_amdgcn_mfma_f32_16x16x32_bf16(
                        a[i][k2], b23[j][k2], acc[i + 2][j + 2], 0, 0, 0);
        __builtin_amdgcn_s_setprio(0);
        __builtin_amdgcn_s_barrier();
        __builtin_amdgcn_sched_barrier(0);

        // ---- P3: stage A u1 (rows 32-63), u3 (rows 96-127); vmcnt(8); MFMA (i23 x j01)
        if (pf) {
            stage_q(Arow + (size_t)32 * lda + kc,   lda, &As[T & 1][2048],     tid);
            stage_q(Arow + (size_t)96 * lda + kc,   lda, &As[T & 1][3 * 2048], tid);
            asm volatile("s_waitcnt vmcnt(8)" ::: "memory");
        } else if (T + 1 < ntiles) {
            asm volatile("s_waitcnt vmcnt(0)" ::: "memory");
        }
        __builtin_amdgcn_s_barrier();
        __builtin_amdgcn_sched_barrier(0);
        __builtin_amdgcn_s_setprio(1);
        #pragma unroll
        for (int i = 0; i < 2; ++i)
            #pragma unroll
            for (int j = 0; j < 2; ++j)
                #pragma unroll
                for (int k2 = 0; k2 < 2; ++k2)
                    acc[i + 2][j] = __builtin_amdgcn_mfma_f32_16x16x32_bf16(
                        a[i][k2], b01[j][k2], acc[i + 2][j], 0, 0, 0);
        __builtin_amdgcn_s_setprio(0);
        __builtin_amdgcn_s_barrier();
        __builtin_amdgcn_sched_barrier(0);
    }

    const int quad = lane >> 4;
    #pragma unroll
    for (int i = 0; i < 4; ++i) {
        #pragma unroll
        for (int j = 0; j < 4; ++j) {
            const int col = bn + wcol + j * 16 + fr;
            #pragma unroll
            for (int r = 0; r < 4; ++r) {
                const int row = bm + wrow + i * 16 + quad * 4 + r;
                Cmat[(size_t)row * ldc + col] = acc[i][j][r];
            }
        }
    }
}

// ---------------------------------------------------------------------------
// Fused flat prep: 4 weight casts + x-last cast + 2 bias concats, one launch.
// ---------------------------------------------------------------------------
#define WG ((CC*CHIN)/4)       // 524288
#define XG ((BB*CHIN)/4)       // 2097152
#define PREP_BLOCKS ((4*WG + XG + 1024) / 256)   // 16388

__device__ __forceinline__ void store_bf4(__hip_bfloat16* dst, float4 vv) {
    union { __hip_bfloat16 h[4]; unsigned long long u; } pk;
    pk.h[0] = (__hip_bfloat16)vv.x; pk.h[1] = (__hip_bfloat16)vv.y;
    pk.h[2] = (__hip_bfloat16)vv.z; pk.h[3] = (__hip_bfloat16)vv.w;
    *(unsigned long long*)dst = pk.u;
}

__global__ __launch_bounds__(256) void prep_flat(
    const float* __restrict__ Wk, const float* __restrict__ Wv,
    const float* __restrict__ WEk, const float* __restrict__ WEv,
    const float* __restrict__ x,
    const float* __restrict__ bk, const float* __restrict__ bv,
    const float* __restrict__ bEk, const float* __restrict__ bEv,
    __hip_bfloat16* __restrict__ Wkvb, __hip_bfloat16* __restrict__ WEkvb,
    __hip_bfloat16* __restrict__ xb,
    float* __restrict__ bkv, float* __restrict__ bEkv)
{
    const int gidx = blockIdx.x * 256 + threadIdx.x;
    if (gidx < 4 * WG) {
        const int mat = gidx >> 19;
        const int off = (gidx & (WG - 1)) * 4;
        const float* src = (mat == 0) ? Wk : (mat == 1) ? Wv : (mat == 2) ? WEk : WEv;
        __hip_bfloat16* dst = (mat < 2) ? (Wkvb + (size_t)mat * (CC * CHIN))
                                        : (WEkvb + (size_t)(mat - 2) * (CC * CHIN));
        store_bf4(dst + off, *(const float4*)(src + off));
    } else if (gidx < 4 * WG + XG) {
        const int off = (gidx - 4 * WG) * 4;
        const int b = off >> 11;
        const int i = off & (CHIN - 1);
        store_bf4(xb + off, *(const float4*)(x + ((size_t)b * TT + TT - 1) * CHIN + i));
    } else {
        const int off = (gidx - 4 * WG - XG) * 4;
        #pragma unroll
        for (int e = 0; e < 4; ++e) {
            const int t = off + e;
            if (t < 2 * CC) bkv[t]  = (t < CC) ? bk[t] : bv[t - CC];
            else { const int u2 = t - 2 * CC; bEkv[u2] = (u2 < CC) ? bEk[u2] : bEv[u2 - CC]; }
        }
    }
}

// static[k][i][n] (fp32) -> staticT[k*NN+n][i] (bf16)
__global__ void transpose_static(const float* __restrict__ st,
                                 __hip_bfloat16* __restrict__ stT)
{
    __shared__ float tile[32][33];
    const int k  = blockIdx.z;
    const int i0 = blockIdx.x * 32;
    const int n0 = blockIdx.y * 32;
    const int tx = threadIdx.x, ty = threadIdx.y;   // 32 x 8
    #pragma unroll
    for (int r = 0; r < 32; r += 8)
        tile[ty + r][tx] = st[((size_t)k * CHIN + i0 + ty + r) * NN + n0 + tx];
    __syncthreads();
    #pragma unroll
    for (int r = 0; r < 32; r += 8)
        stT[((size_t)k * NN + n0 + ty + r) * CHIN + i0 + tx] = (__hip_bfloat16)tile[tx][ty + r];
}

// Ev transpose straight from fp32 Ekv (cols CC..2CC): EvC[c][kn] = bf16(Ekv[kn][CC+c])
__global__ void transpose_Ev(const float* __restrict__ Ekv,
                             __hip_bfloat16* __restrict__ EvC)
{
    __shared__ float tile[32][33];
    const int c0  = blockIdx.x * 32;
    const int kn0 = blockIdx.y * 32;
    const int tx = threadIdx.x, ty = threadIdx.y;   // 32 x 8
    #pragma unroll
    for (int r = 0; r < 32; r += 8)
        tile[ty + r][tx] = Ekv[(size_t)(kn0 + ty + r) * (2 * CC) + CC + c0 + tx];
    __syncthreads();
    #pragma unroll
    for (int r = 0; r < 32; r += 8)
        EvC[(size_t)(c0 + ty + r) * KN + kn0 + tx] = (__hip_bfloat16)tile[tx][ty + r];
}

// Merged per-kn-row pass over Ekv, single read: EknT = normalized Ek (bf16); g = Ww.Ev
__global__ __launch_bounds__(256) void norm_prep_E(const float* __restrict__ Ekv,
                                                   const float* __restrict__ Ww,
                                                   __hip_bfloat16* __restrict__ EknT,
                                                   float* __restrict__ g)
{
    const int kn = blockIdx.x;
    const int t  = threadIdx.x;
    const float* pk = Ekv + (size_t)kn * (2 * CC);
    const float4 ek = ((const float4*)pk)[t];
    const float4 ev = ((const float4*)(pk + CC))[t];
    const float4 ww = ((const float4*)Ww)[t];
    float s2 = ek.x*ek.x + ek.y*ek.y + ek.z*ek.z + ek.w*ek.w;
    float sg = ww.x*ev.x + ww.y*ev.y + ww.z*ev.z + ww.w*ev.w;
    #pragma unroll
    for (int o = 32; o > 0; o >>= 1) { s2 += __shfl_down(s2, o, 64); sg += __shfl_down(sg, o, 64); }
    __shared__ float r2[4], rg[4];
    if ((t & 63) == 0) { r2[t >> 6] = s2; rg[t >> 6] = sg; }
    __syncthreads();
    const float tot = r2[0] + r2[1] + r2[2] + r2[3];
    const float inv = 1.f / fmaxf(sqrtf(tot), 1e-8f);
    store_bf4(EknT + (size_t)kn * CC + t * 4,
              make_float4(ek.x * inv, ek.y * inv, ek.z * inv, ek.w * inv));
    if (t == 0) g[kn] = rg[0] + rg[1] + rg[2] + rg[3];
}

// Single-read L2-normalize: row of kv (first CC cols) -> bf16 kn row.
__global__ __launch_bounds__(256) void rownorm(const float* __restrict__ in, int in_ld,
                                               __hip_bfloat16* __restrict__ out)
{
    const int row = blockIdx.x;
    const int t   = threadIdx.x;
    const float4 v = ((const float4*)(in + (size_t)row * in_ld))[t];
    float s = v.x*v.x + v.y*v.y + v.z*v.z + v.w*v.w;
    #pragma unroll
    for (int o = 32; o > 0; o >>= 1) s += __shfl_down(s, o, 64);
    __shared__ float red[4];
    if ((t & 63) == 0) red[t >> 6] = s;
    __syncthreads();
    const float tot = red[0] + red[1] + red[2] + red[3];
    const float inv = 1.f / fmaxf(sqrtf(tot), 1e-8f);
    store_bf4(out + (size_t)row * CC + t * 4,
              make_float4(v.x * inv, v.y * inv, v.z * inv, v.w * inv));
}

// per (b,k): softmax over 512 WITHOUT max subtraction (sim = cosine in [-1,1],
// exp in [e^-1, e] -> no overflow possible), fw = sigmoid(dot(w,g)+bw), u = w*fw.
__global__ __launch_bounds__(256) void softmax_u(const float* __restrict__ sim,
                                                 const float* __restrict__ g,
                                                 const float* __restrict__ bw,
                                                 __hip_bfloat16* __restrict__ u)
{
    const int bk = blockIdx.x * 4 + (threadIdx.x >> 6);
    const int b = bk / KK, k = bk % KK;
    const float* sp = sim + (size_t)b * KN + k * NN;
    const float* gp = g + k * NN;
    const int lane = threadIdx.x & 63;

    const float4 v0 = ((const float4*)sp)[lane * 2];
    const float4 v1 = ((const float4*)sp)[lane * 2 + 1];
    float vals[8] = {v0.x, v0.y, v0.z, v0.w, v1.x, v1.y, v1.z, v1.w};
    float sum = 0.f;
    #pragma unroll
    for (int j = 0; j < 8; ++j) { vals[j] = expf(vals[j]); sum += vals[j]; }
    #pragma unroll
    for (int o = 32; o > 0; o >>= 1) sum += __shfl_xor(sum, o, 64);
    const float inv = 1.f / sum;
    const float4 g0 = ((const float4*)gp)[lane * 2];
    const float4 g1 = ((const float4*)gp)[lane * 2 + 1];
    const float gv[8] = {g0.x, g0.y, g0.z, g0.w, g1.x, g1.y, g1.z, g1.w};
    float dot = 0.f;
    #pragma unroll
    for (int j = 0; j < 8; ++j) { vals[j] *= inv; dot += vals[j] * gv[j]; }
    #pragma unroll
    for (int o = 32; o > 0; o >>= 1) dot += __shfl_xor(dot, o, 64);
    const float fw = 1.f / (1.f + expf(-(dot + bw[0])));
    union { __hip_bfloat16 h[8]; bf16x8 v; } pk;
    #pragma unroll
    for (int j = 0; j < 8; ++j) pk.h[j] = (__hip_bfloat16)(vals[j] * fw);
    *(bf16x8*)(u + (size_t)b * KN + k * NN + lane * 8) = pk.v;
}

// out[b][kk] = bout[kk] + sum_c Wout[kk][c]*relu(v[c]) + Wout[kk][CC+c]*relu(fE0+fE1)
__global__ __launch_bounds__(256) void final_out(const float* __restrict__ kv,
                                                 const float* __restrict__ fE0,
                                                 const float* __restrict__ fE1,
                                                 const float* __restrict__ Wout,
                                                 const float* __restrict__ bout,
                                                 float* __restrict__ out)
{
    const int b = blockIdx.x;
    const int t = threadIdx.x;
    const float4 v4 = ((const float4*)(kv + (size_t)b * (2 * CC) + CC))[t];
    const float4 a0 = ((const float4*)(fE0 + (size_t)b * CC))[t];
    const float4 a1 = ((const float4*)(fE1 + (size_t)b * CC))[t];
    const float rv[4] = {fmaxf(v4.x, 0.f), fmaxf(v4.y, 0.f), fmaxf(v4.z, 0.f), fmaxf(v4.w, 0.f)};
    const float rf[4] = {fmaxf(a0.x + a1.x, 0.f), fmaxf(a0.y + a1.y, 0.f),
                         fmaxf(a0.z + a1.z, 0.f), fmaxf(a0.w + a1.w, 0.f)};
    float acc[KK];
    #pragma unroll
    for (int kk = 0; kk < KK; ++kk) {
        const float4 wv = ((const float4*)(Wout + (size_t)kk * 2 * CC))[t];
        const float4 wf = ((const float4*)(Wout + (size_t)kk * 2 * CC + CC))[t];
        acc[kk] = wv.x * rv[0] + wv.y * rv[1] + wv.z * rv[2] + wv.w * rv[3]
                + wf.x * rf[0] + wf.y * rf[1] + wf.z * rf[2] + wf.w * rf[3];
    }
    __shared__ float red[KK][4];
    const int lane = t & 63, wave = t >> 6;
    #pragma unroll
    for (int kk = 0; kk < KK; ++kk) {
        float s = acc[kk];
        #pragma unroll
        for (int o = 32; o > 0; o >>= 1) s += __shfl_down(s, o, 64);
        if (lane == 0) red[kk][wave] = s;
    }
    __syncthreads();
    if (t < KK) {
        float s = red[t][0] + red[t][1] + red[t][2] + red[t][3];
        out[(size_t)b * KK + t] = s + bout[t];
    }
}

extern "C" void kernel_launch(void* const* d_in, const int* in_sizes, int n_in,
                              void* d_out, int out_size, void* d_ws, size_t ws_size,
                              hipStream_t stream)
{
    const float* x    = (const float*)d_in[0];
    const float* stat = (const float*)d_in[1];
    const float* Wk   = (const float*)d_in[2];
    const float* bk   = (const float*)d_in[3];
    const float* Wv   = (const float*)d_in[4];
    const float* bv   = (const float*)d_in[5];
    const float* WEk  = (const float*)d_in[6];
    const float* bEk  = (const float*)d_in[7];
    const float* WEv  = (const float*)d_in[8];
    const float* bEv  = (const float*)d_in[9];
    const float* Ww   = (const float*)d_in[10];
    const float* bw   = (const float*)d_in[11];
    const float* Wout = (const float*)d_in[12];
    const float* bout = (const float*)d_in[13];
    float* out = (float*)d_out;
    char* ws = (char*)d_ws;

    __hip_bfloat16* xb      = (__hip_bfloat16*)(ws + 0);          // [BB][CHIN]    16.78 MB
    __hip_bfloat16* Wkvb    = (__hip_bfloat16*)(ws + 16777216);   // [2CC][CHIN]    8.39 MB
    __hip_bfloat16* WEkvb   = (__hip_bfloat16*)(ws + 25165824);   // [2CC][CHIN]    8.39 MB
    __hip_bfloat16* staticT = (__hip_bfloat16*)(ws + 33554432);   // [KN][CHIN]    10.49 MB
    float*          Ekv     = (float*)(ws + 44040192);            // [KN][2CC]     20.97 MB
    __hip_bfloat16* EknT    = (__hip_bfloat16*)(ws + 65011712);   // [KN][CC]       5.24 MB
    __hip_bfloat16* EvC     = (__hip_bfloat16*)(ws + 75497472);   // [CC][KN]       5.24 MB
    float*          g       = (float*)(ws + 80740352);            // [KN]           10 KB
    float*          kv      = (float*)(ws + 80750592);            // [BB][2CC]     33.55 MB
    __hip_bfloat16* kn      = (__hip_bfloat16*)(ws + 114305024);  // [BB][CC]       8.39 MB
    float*          sim     = (float*)(ws + 122693632);           // [BB][KN]      41.94 MB
    __hip_bfloat16* u       = (__hip_bfloat16*)(ws + 164636672);  // [BB][KN]      20.97 MB
    float*          fE      = (float*)(ws + 185608192);           // [BB][CC]      16.78 MB
    float*          bkv     = (float*)(ws + 202385408);           // [2CC]          8 KB
    float*          bEkv    = (float*)(ws + 202393600);           // [2CC]          8 KB
    float*          fE2     = (float*)(ws + 202401792);           // [BB][CC]      16.78 MB

    // 0. all flat prep in one launch + static transpose
    prep_flat<<<PREP_BLOCKS, 256, 0, stream>>>(
        Wk, Wv, WEk, WEv, x, bk, bv, bEk, bEv, Wkvb, WEkvb, xb, bkv, bEkv);
    transpose_static<<<dim3(CHIN / 32, NN / 32, KK), dim3(32, 8), 0, stream>>>(stat, staticT);

    // 1+5. Fused: Ekv (M=KN) + kv (M=BB); N=2CC, K=CHIN. Grid (8, 26) = 208.
    gemm8p_dual<<<dim3(2 * CC / BN, KN / BM + BB / BM), 512, 0, stream>>>(
        staticT, WEkvb, Ekv, bEkv, KN / BM,
        xb, Wkvb, kv, bkv);
    // 2+3. Ek row-norm + g, single pass
    norm_prep_E<<<KN, 256, 0, stream>>>(Ekv, Ww, EknT, g);
    // 4. EvC[c][kn] = bf16(Ekv[kn][CC+c])
    transpose_Ev<<<dim3(CC / 32, KN / 32), dim3(32, 8), 0, stream>>>(Ekv, EvC);
    // 6. kn = rownormalize(k_pre), single pass
    rownorm<<<BB, 256, 0, stream>>>(kv, 2 * CC, kn);
    // 7. sim = kn @ EknT^T  (M=BB, N=KN, K=CC). Grid (10, 16) = 160.
    gemm8p<<<dim3(KN / BN, BB / BM), 512, 0, stream>>>(
        kn, CC, EknT, CC, sim, KN, CC / 64, nullptr);
    // 8. softmax (max-free) + fw -> u (bf16)
    softmax_u<<<BB * KK / 4, 256, 0, stream>>>(sim, g, bw, u);
    // 9. fE partials = u @ EvC^T  (M=BB, N=CC, K=KN, 128^2 split-K=2).
    //    Grid (8, 32, 2) = 512 blocks = 2 blocks/CU.
    gemm128_splitk2<<<dim3(CC / 128, BB / 128, 2), 256, 0, stream>>>(
        u, KN, EvC, KN, fE, fE2, CC, (KN / 2) / 64);
    // 10. out = relu([v, fE+fE2]) @ Wout^T + bout (fp32 out)
    final_out<<<BB, 256, 0, stream>>>(kv, fE, fE2, Wout, bout, out);
}